// Round 6
// baseline (303.856 us; speedup 1.0000x reference)
//
#include <hip/hip_runtime.h>

#define DEV static __device__ __forceinline__

typedef __attribute__((ext_vector_type(8))) short bf16x8;
typedef __attribute__((ext_vector_type(4))) float f32x4;

#define MFMA(a, b, c) __builtin_amdgcn_mfma_f32_16x16x32_bf16(a, b, c, 0, 0, 0)

DEV float bf2f(unsigned short h) { return __uint_as_float(((unsigned)h) << 16); }
DEV unsigned short f2bf(float f) {
  unsigned u = __float_as_uint(f);
  u += 0x7fffu + ((u >> 16) & 1u);
  return (unsigned short)(u >> 16);
}
DEV bf16x8 ld8(const unsigned short* p) { return *(const bf16x8*)p; }

DEV void load_row64f(const float* p, float* w) {
  const float4* v = (const float4*)p;
  #pragma unroll
  for (int c = 0; c < 16; ++c) {
    float4 u = v[c];
    w[4*c+0] = u.x; w[4*c+1] = u.y; w[4*c+2] = u.z; w[4*c+3] = u.w;
  }
}
DEV float dot64(const float* x, const float* w) {
  float a0 = 0.f, a1 = 0.f, a2 = 0.f, a3 = 0.f;
  #pragma unroll
  for (int d = 0; d < 64; d += 4) {
    a0 = fmaf(x[d+0], w[d+0], a0); a1 = fmaf(x[d+1], w[d+1], a1);
    a2 = fmaf(x[d+2], w[d+2], a2); a3 = fmaf(x[d+3], w[d+3], a3);
  }
  return (a0+a1)+(a2+a3);
}
DEV float wred64(float v) {
  #pragma unroll
  for (int o = 32; o > 0; o >>= 1) v += __shfl_xor(v, o, 64);
  return v;
}

// d_ws layout (ushort element offsets): weights as bf16 hi/lo pairs
#define XW_HI 0        // 4*2*128*64 = 65536
#define XW_LO 65536
#define OW_HI 131072   // 4*2*64*64 = 32768
#define OW_LO 163840
#define MW_HI 196608   // 4*64*128 = 32768
#define MW_LO 229376
#define AI_HI 262144   // 192*64 = 12288
#define AI_LO 274432
#define SC_OFF 286720  // f32 region: 8*256 gate-poly coefs

#define SF 68  // f32 seq row stride (272 B: 16B-aligned, 2-way banks = free)
#define SB 72  // bf16 row stride (144 B: 16B-aligned for ds_read_b128)

__global__ void prep_kernel(const float* __restrict__ xW, const float* __restrict__ oW,
                            const float* __restrict__ mW, const float* __restrict__ aiW,
                            const float* __restrict__ Ap, unsigned short* __restrict__ wsb) {
  const int gid = blockIdx.x * blockDim.x + threadIdx.x;
  const int stride = gridDim.x * blockDim.x;
  for (int i = gid; i < 65536; i += stride) {
    float x = xW[i]; unsigned short h = f2bf(x);
    wsb[XW_HI + i] = h; wsb[XW_LO + i] = f2bf(x - bf2f(h));
  }
  for (int i = gid; i < 32768; i += stride) {
    float x = oW[i]; unsigned short h = f2bf(x);
    wsb[OW_HI + i] = h; wsb[OW_LO + i] = f2bf(x - bf2f(h));
  }
  for (int i = gid; i < 32768; i += stride) {
    float x = mW[i]; unsigned short h = f2bf(x);
    wsb[MW_HI + i] = h; wsb[MW_LO + i] = f2bf(x - bf2f(h));
  }
  for (int i = gid; i < 12288; i += stride) {
    float x = aiW[i]; unsigned short h = f2bf(x);
    wsb[AI_HI + i] = h; wsb[AI_LO + i] = f2bf(x - bf2f(h));
  }
  float* sc = (float*)(wsb + SC_OFF);
  for (int i = gid; i < 512; i += stride) {
    int pi = i >> 6, d = i & 63;
    const float* a = Ap + (size_t)i * 16;
    float s1 = 0, s2 = 0, s3 = 0, s4 = 0;
    #pragma unroll
    for (int n = 0; n < 16; ++n) {
      float z = a[n]; float z2 = z * z;
      s1 += z; s2 += z2; s3 += z2 * z; s4 += z2 * z2;
    }
    sc[pi*256 + d]       = s1;
    sc[pi*256 + 64 + d]  = s2 * 0.5f;
    sc[pi*256 + 128 + d] = s3 * (1.f/6.f);
    sc[pi*256 + 192 + d] = s4 * (1.f/24.f);
  }
}

// B=1024, ND=13, NS=26, V=10000, D=64, H=8, N=16, NL=4, SEQ=40
// launch_bounds arg=3: toolchain caps VGPR at ~84 (observed R3/R4, spill-free).
// arg=4 capped at 64 and spilled h[20]/w[64] -> 156 MB scratch traffic (R5).
// VGPR 84 <= 128 still allows 4 waves/SIMD, so LDS (40,832 <= 40,960) sets
// occupancy at 4 blocks/CU.
__global__ __launch_bounds__(256, 3)
void Mamba4CTRV3_kernel(
    const float* __restrict__ dense_x, const float* __restrict__ dense_W,
    const float* __restrict__ dense_b, const float* __restrict__ tbl,
    const float* __restrict__ cls, const float* __restrict__ ng,
    const float* __restrict__ nb, const float* __restrict__ xb,
    const float* __restrict__ Dp, const float* __restrict__ ob,
    const float* __restrict__ mb, const float* __restrict__ aib,
    const float* __restrict__ aoW, const float* __restrict__ aob,
    const float* __restrict__ w1, const float* __restrict__ b1,
    const float* __restrict__ w2, const float* __restrict__ b2,
    const float* __restrict__ w3, const float* __restrict__ b3,
    const int* __restrict__ sidx, const unsigned short* __restrict__ wsb,
    float* __restrict__ out) {
  // LDS 40,832 B -> 4 blocks/CU (163,840/4 = 40,960 cap).
  // 128 B tail pad: MFMA A-frag reads touch "rows" 40..47 (discarded);
  // last buffer's overshoot must stay inside the allocation.
  __shared__ __align__(16) unsigned char smem[40832];
  float*          s_seq  = (float*)smem;                     // 40xSF f32 residual spine
  unsigned short* s_xnb  = (unsigned short*)(smem + 10880);  // 40xSB bf16 xn / final seq
  unsigned short* bG0    = (unsigned short*)(smem + 16640);  // gate0 -> out0 ; tail f32 scratch A
  unsigned short* bG1    = (unsigned short*)(smem + 22400);  // gate1 -> out1 ; tail f32 scratch B
  unsigned short* bB0    = (unsigned short*)(smem + 28160);  // Bm0 -> f-branch ; tail: K bf16
  unsigned short* bB1    = (unsigned short*)(smem + 33920);  // Bm1 -> r-branch ; tail: V bf16
  float*          s_small= (float*)(smem + 39680);           // 256 f32 (seg totals; ph0 dx/idx)
  float* g0f = (float*)bG0;
  float* g1f = (float*)bG1;
  const float* scf = (const float*)(wsb + SC_OFF);

  const int tid = threadIdx.x, b = blockIdx.x;
  const int lane = tid & 63, wv = tid >> 6;
  const int arow = lane & 15;      // A-frag row / C-frag col
  const int aq = (lane >> 4) * 8;  // A-frag k offset
  const int rq = (lane >> 4) * 4;  // C-frag row base

  // ---------------- Phase 0: build seq (f32) ----------------
  {
    float* s_dx = s_small;
    int* s_idx = (int*)(s_small + 16);
    if (tid < 13) s_dx[tid] = dense_x[b*13 + tid];
    if (tid >= 64 && tid < 90) {
      int s = tid - 64;
      int v = sidx[b*26 + s];
      v = v < 0 ? 0 : (v > 10000 ? 10000 : v);
      s_idx[s] = v;
    }
    __syncthreads();
    if (tid < 64) s_seq[tid] = cls[tid];
    {
      float x[13];
      #pragma unroll
      for (int k = 0; k < 13; ++k) x[k] = s_dx[k];
      for (int j = tid; j < 832; j += 256) {
        float acc = dense_b[j];
        #pragma unroll
        for (int k = 0; k < 13; ++k) acc = fmaf(x[k], dense_W[j*13 + k], acc);
        s_seq[(1 + (j >> 6)) * SF + (j & 63)] = acc;
      }
    }
    for (int e = tid; e < 26*16; e += 256) {
      int s = e >> 4, c = e & 15;
      const float4* row = (const float4*)(tbl + ((size_t)(s*10001 + s_idx[s]))*64);
      ((float4*)&s_seq[(14 + s) * SF])[c] = row[c];
    }
  }
  __syncthreads();

  // ---------------- 4 bidirectional mamba layers (dirs fused) ----------------
  for (int L = 0; L < 4; ++L) {
    const int pi0 = 2*L, pi1 = 2*L + 1;

    // LN once per layer (rev branch LN == same per-token values)
    {
      const int half = lane >> 5, dl = lane & 31;
      for (int it = 0; it < 5; ++it) {
        int t = wv*10 + it*2 + half;
        int e = t*SF + dl;
        float x0 = s_seq[e], x1 = s_seq[e + 32];
        float s = x0 + x1, q = fmaf(x0, x0, x1*x1);
        #pragma unroll
        for (int o = 16; o > 0; o >>= 1) { s += __shfl_xor(s, o, 64); q += __shfl_xor(q, o, 64); }
        float mean = s * (1.f/64.f);
        float var = q * (1.f/64.f) - mean*mean;
        float rs = rsqrtf(var + 1e-5f);
        float xn0 = fmaf((x0 - mean) * rs, ng[pi0*64 + dl], nb[pi0*64 + dl]);
        float xn1 = fmaf((x1 - mean) * rs, ng[pi0*64 + dl + 32], nb[pi0*64 + dl + 32]);
        int eb = t*SB + dl;
        s_xnb[eb] = f2bf(xn0); s_xnb[eb + 32] = f2bf(xn1);
      }
    }
    __syncthreads();

    // xproj both dirs: pass0 = delta cols (0..63), pass1 = Bm cols (64..127)
    #pragma unroll 1
    for (int p = 0; p < 2; ++p) {
      const int j = (wv + 4*p)*16 + arow;  // 0..63 (p=0) / 64..127 (p=1)
      const unsigned short* Wh0 = wsb + XW_HI + pi0*8192 + j*64;
      const unsigned short* Wl0 = wsb + XW_LO + pi0*8192 + j*64;
      const unsigned short* Wh1 = wsb + XW_HI + pi1*8192 + j*64;
      const unsigned short* Wl1 = wsb + XW_LO + pi1*8192 + j*64;
      bf16x8 bh00 = ld8(Wh0 + aq), bh01 = ld8(Wh0 + 32 + aq);
      bf16x8 bl00 = ld8(Wl0 + aq), bl01 = ld8(Wl0 + 32 + aq);
      bf16x8 bh10 = ld8(Wh1 + aq), bh11 = ld8(Wh1 + 32 + aq);
      bf16x8 bl10 = ld8(Wl1 + aq), bl11 = ld8(Wl1 + 32 + aq);
      const float bj0 = xb[pi0*128 + j], bj1 = xb[pi1*128 + j];
      float c10=0,c20=0,c30=0,c40=0,c11=0,c21=0,c31=0,c41=0;
      if (p == 0) {
        c10=scf[pi0*256+j]; c20=scf[pi0*256+64+j]; c30=scf[pi0*256+128+j]; c40=scf[pi0*256+192+j];
        c11=scf[pi1*256+j]; c21=scf[pi1*256+64+j]; c31=scf[pi1*256+128+j]; c41=scf[pi1*256+192+j];
      }
      for (int mt = 0; mt < 3; ++mt) {
        const unsigned short* A = s_xnb + (mt*16 + arow)*SB + aq;
        bf16x8 ah0 = ld8(A), ah1 = ld8(A + 32);
        f32x4 a0 = {0,0,0,0}, a1 = {0,0,0,0};
        a0 = MFMA(ah0, bh00, a0); a0 = MFMA(ah0, bl00, a0);
        a0 = MFMA(ah1, bh01, a0); a0 = MFMA(ah1, bl01, a0);
        a1 = MFMA(ah0, bh10, a1); a1 = MFMA(ah0, bl10, a1);
        a1 = MFMA(ah1, bh11, a1); a1 = MFMA(ah1, bl11, a1);
        const int rbase = mt*16 + rq;
        #pragma unroll
        for (int r = 0; r < 4; ++r) {
          int row = rbase + r;
          if (row >= 40) break;
          float x0v = a0[r] + bj0, x1v = a1[r] + bj1;
          if (p == 0) {  // delta -> gate deviation (bf16)
            float sp0 = fmaxf(x0v, 0.f) + __logf(1.f + __expf(-fabsf(x0v)));
            float sp1 = fmaxf(x1v, 0.f) + __logf(1.f + __expf(-fabsf(x1v)));
            bG0[row*SB + j] = f2bf(sp0 * fmaf(sp0, fmaf(sp0, fmaf(sp0, c40, c30), c20), c10));
            bG1[row*SB + j] = f2bf(sp1 * fmaf(sp1, fmaf(sp1, fmaf(sp1, c41, c31), c21), c11));
          } else {       // raw Bm (bf16)
            int d = j - 64;
            bB0[row*SB + d] = f2bf(x0v);
            bB1[row*SB + d] = f2bf(x1v);
          }
        }
      }
    }
    __syncthreads();

    // Scan Da: register-resident segmented scan, both dirs (2 segs x 20 tokens)
    {
      const int dd = tid & 127, seg = tid >> 7;
      const int dir = dd >> 6, d = dd & 63;
      const unsigned short* bmb = dir ? bB1 : bB0;
      unsigned short* gb = dir ? bG1 : bG0;
      float h[20], run = 0.f;
      #pragma unroll
      for (int k = 0; k < 20; ++k) {
        int t = dir ? (39 - (seg*20 + k)) : (seg*20 + k);
        run += bf2f(s_xnb[t*SB + d]) * bf2f(bmb[t*SB + d]);
        h[k] = run;
      }
      s_small[seg*128 + dd] = run;
      __syncthreads();
      // Db: carry + out = h*gate + xn*Dp -> in-place over gate slots (bf16)
      const float off = seg ? s_small[dd] : 0.f;
      const float dpd = Dp[(2*L + dir)*64 + d];
      #pragma unroll
      for (int k = 0; k < 20; ++k) {
        int t = dir ? (39 - (seg*20 + k)) : (seg*20 + k);
        float gate = 16.f + bf2f(gb[t*SB + d]);
        float xn = bf2f(s_xnb[t*SB + d]);
        gb[t*SB + d] = f2bf(fmaf(h[k] + off, gate, xn * dpd));
      }
    }
    __syncthreads();

    // outproj both dirs + residual -> bB0 (fwd) / bB1 (rev), bf16
    {
      const int j = wv*16 + arow;
      const unsigned short* Wh0 = wsb + OW_HI + pi0*4096 + j*64;
      const unsigned short* Wl0 = wsb + OW_LO + pi0*4096 + j*64;
      const unsigned short* Wh1 = wsb + OW_HI + pi1*4096 + j*64;
      const unsigned short* Wl1 = wsb + OW_LO + pi1*4096 + j*64;
      bf16x8 bh00 = ld8(Wh0 + aq), bh01 = ld8(Wh0 + 32 + aq);
      bf16x8 bl00 = ld8(Wl0 + aq), bl01 = ld8(Wl0 + 32 + aq);
      bf16x8 bh10 = ld8(Wh1 + aq), bh11 = ld8(Wh1 + 32 + aq);
      bf16x8 bl10 = ld8(Wl1 + aq), bl11 = ld8(Wl1 + 32 + aq);
      const float bo0 = ob[pi0*64 + j], bo1 = ob[pi1*64 + j];
      for (int mt = 0; mt < 3; ++mt) {
        const unsigned short* A0 = bG0 + (mt*16 + arow)*SB + aq;
        const unsigned short* A1 = bG1 + (mt*16 + arow)*SB + aq;
        bf16x8 a00 = ld8(A0), a01 = ld8(A0 + 32);
        bf16x8 a10 = ld8(A1), a11 = ld8(A1 + 32);
        f32x4 c0 = {0,0,0,0}, c1 = {0,0,0,0};
        c0 = MFMA(a00, bh00, c0); c0 = MFMA(a00, bl00, c0);
        c0 = MFMA(a01, bh01, c0); c0 = MFMA(a01, bl01, c0);
        c1 = MFMA(a10, bh10, c1); c1 = MFMA(a10, bl10, c1);
        c1 = MFMA(a11, bh11, c1); c1 = MFMA(a11, bl11, c1);
        const int rbase = mt*16 + rq;
        #pragma unroll
        for (int r = 0; r < 4; ++r) {
          int row = rbase + r;
          if (row >= 40) break;
          float res = s_seq[row*SF + j];
          bB0[row*SB + j] = f2bf(c0[r] + bo0 + res);
          bB1[row*SB + j] = f2bf(c1[r] + bo1 + res);
        }
      }
    }
    __syncthreads();

    // merge: seq = [f, r] @ mW.T + mb -> s_seq f32 (+ s_xnb bf16 after last layer)
    {
      const int n0 = wv*16 + arow;
      const unsigned short* Wh = wsb + MW_HI + L*8192 + n0*128;
      const unsigned short* Wl = wsb + MW_LO + L*8192 + n0*128;
      bf16x8 bh[4], bl[4];
      #pragma unroll
      for (int ks = 0; ks < 4; ++ks) { bh[ks] = ld8(Wh + ks*32 + aq); bl[ks] = ld8(Wl + ks*32 + aq); }
      const float bo = mb[L*64 + n0];
      for (int mt = 0; mt < 3; ++mt) {
        const unsigned short* Af = bB0 + (mt*16 + arow)*SB + aq;
        const unsigned short* Ar = bB1 + (mt*16 + arow)*SB + aq;
        bf16x8 fh0 = ld8(Af), fh1 = ld8(Af + 32);
        bf16x8 rh0 = ld8(Ar), rh1 = ld8(Ar + 32);
        f32x4 a0 = {0,0,0,0};
        a0 = MFMA(fh0, bh[0], a0); a0 = MFMA(fh0, bl[0], a0);
        a0 = MFMA(fh1, bh[1], a0); a0 = MFMA(fh1, bl[1], a0);
        a0 = MFMA(rh0, bh[2], a0); a0 = MFMA(rh0, bl[2], a0);
        a0 = MFMA(rh1, bh[3], a0); a0 = MFMA(rh1, bl[3], a0);
        const int rbase = mt*16 + rq;
        #pragma unroll
        for (int r = 0; r < 4; ++r) {
          int row = rbase + r;
          if (row >= 40) break;
          float v = a0[r] + bo;
          s_seq[row*SF + n0] = v;
          if (L == 3) s_xnb[row*SB + n0] = f2bf(v);
        }
      }
    }
    __syncthreads();
  }

  // ---------------- Attention tail (token 0 only consumed downstream) ----------------
  // QKV, balanced: 28 (col-tile, mt) units round-robin over 4 waves.
  // q(row0) -> g0f[320..384), K bf16 -> bB0, V bf16 -> bB1, c=seq0 -> g0f[384..448)
  {
    #pragma unroll 1
    for (int i = 0; i < 7; ++i) {
      const int u = wv + 4*i;
      int jt, mt;
      if (u < 4) { jt = u; mt = 0; }
      else { int v = u - 4; jt = 4 + (v & 7); mt = v >> 3; }
      const int j = jt*16 + arow;
      const unsigned short* Wh = wsb + AI_HI + j*64;
      const unsigned short* Wl = wsb + AI_LO + j*64;
      bf16x8 bh0 = ld8(Wh + aq), bh1 = ld8(Wh + 32 + aq);
      bf16x8 bl0 = ld8(Wl + aq), bl1 = ld8(Wl + 32 + aq);
      const float bj = aib[j];
      const unsigned short* A = s_xnb + (mt*16 + arow)*SB + aq;
      bf16x8 ah0 = ld8(A), ah1 = ld8(A + 32);
      f32x4 a0 = {0,0,0,0};
      a0 = MFMA(ah0, bh0, a0); a0 = MFMA(ah0, bl0, a0);
      a0 = MFMA(ah1, bh1, a0); a0 = MFMA(ah1, bl1, a0);
      const int rbase = mt*16 + rq;
      #pragma unroll
      for (int r = 0; r < 4; ++r) {
        int row = rbase + r;
        if (row >= 40) break;
        float val = a0[r] + bj;
        if (jt < 4) { if (row == 0) g0f[320 + j] = val; }
        else if (jt < 8) bB0[row*SB + (j - 64)] = f2bf(val);
        else bB1[row*SB + (j - 128)] = f2bf(val);
      }
    }
    if (tid >= 192) g0f[384 + (tid - 192)] = s_seq[tid - 192];
  }
  __syncthreads();

  // logits (8 heads x 40 keys) -> g0f[0..320)
  for (int e = tid; e < 320; e += 256) {
    int h = e / 40, kk = e - h*40;
    float acc = 0.f;
    #pragma unroll
    for (int i = 0; i < 8; ++i)
      acc += g0f[320 + h*8 + i] * bf2f(bB0[kk*SB + h*8 + i]);
    g0f[e] = acc * 0.35355339059327373f;
  }
  __syncthreads();

  // softmax: 2 heads per wave, 32 lanes per head
  {
    const int h = wv*2 + (lane >> 5), jl = lane & 31;
    float a = g0f[h*40 + jl];
    float bv = (jl < 8) ? g0f[h*40 + 32 + jl] : -1e30f;
    float m = fmaxf(a, bv);
    #pragma unroll
    for (int o = 16; o > 0; o >>= 1) m = fmaxf(m, __shfl_xor(m, o, 32));
    float pa = __expf(a - m), pb = (jl < 8) ? __expf(bv - m) : 0.f;
    float s = pa + pb;
    #pragma unroll
    for (int o = 16; o > 0; o >>= 1) s += __shfl_xor(s, o, 32);
    float inv = 1.f / s;
    g0f[h*40 + jl] = pa * inv;
    if (jl < 8) g0f[h*40 + 32 + jl] = pb * inv;
  }
  __syncthreads();

  // ao partials over 256 threads -> g1f[0..256)
  {
    const int d = tid & 63, qrt = tid >> 6, hh = d >> 3;
    float acc = 0.f;
    #pragma unroll
    for (int k = qrt*10; k < qrt*10 + 10; ++k)
      acc += g0f[hh*40 + k] * bf2f(bB1[k*SB + d]);
    g1f[qrt*64 + d] = acc;
  }
  __syncthreads();
  if (tid < 64) g1f[256 + tid] = g1f[tid] + g1f[64 + tid] + g1f[128 + tid] + g1f[192 + tid];
  __syncthreads();

  // c = seq0 + ao @ aoW.T + aob -> g0f[448..512)
  if (tid < 64) {
    float w[64];
    load_row64f(aoW + (size_t)tid*64, w);
    g0f[448 + tid] = g0f[384 + tid] + aob[tid] + dot64(&g1f[256], w);
  }
  __syncthreads();

  // MLP1 -> g1f[320..448)
  if (tid < 128) {
    float w[64];
    load_row64f(w1 + (size_t)tid*64, w);
    g1f[320 + tid] = fmaxf(b1[tid] + dot64(&g0f[448], w), 0.f);
  }
  __syncthreads();

  // MLP2 -> g1f[448..512)
  if (tid < 64) {
    float w[64];
    load_row64f(w2 + (size_t)tid*128, w);
    float acc = dot64(&g1f[320], w);
    load_row64f(w2 + (size_t)tid*128 + 64, w);
    acc += dot64(&g1f[384], w);
    g1f[448 + tid] = fmaxf(acc + b2[tid], 0.f);
  }
  __syncthreads();

  if (tid < 64) {
    float v = g1f[448 + tid] * w3[tid];
    v = wred64(v);
    if (tid == 0) out[b] = v + b3[0];
  }
}

extern "C" void kernel_launch(void* const* d_in, const int* in_sizes, int n_in,
                              void* d_out, int out_size, void* d_ws, size_t ws_size,
                              hipStream_t stream) {
  (void)n_in; (void)ws_size; (void)out_size;
  const float* dense_x = (const float*)d_in[0];
  const float* dense_W = (const float*)d_in[1];
  const float* dense_b = (const float*)d_in[2];
  const float* tbl     = (const float*)d_in[3];
  const float* cls     = (const float*)d_in[4];
  const float* ng      = (const float*)d_in[5];
  const float* nb      = (const float*)d_in[6];
  const float* xW      = (const float*)d_in[7];
  const float* xb      = (const float*)d_in[8];
  const float* Ap      = (const float*)d_in[9];
  const float* Dp      = (const float*)d_in[10];
  const float* oW      = (const float*)d_in[11];
  const float* ob      = (const float*)d_in[12];
  const float* mW      = (const float*)d_in[13];
  const float* mb      = (const float*)d_in[14];
  const float* aiW     = (const float*)d_in[15];
  const float* aib     = (const float*)d_in[16];
  const float* aoW     = (const float*)d_in[17];
  const float* aob     = (const float*)d_in[18];
  const float* w1      = (const float*)d_in[19];
  const float* b1      = (const float*)d_in[20];
  const float* w2      = (const float*)d_in[21];
  const float* b2      = (const float*)d_in[22];
  const float* w3      = (const float*)d_in[23];
  const float* b3      = (const float*)d_in[24];
  const int*   sidx    = (const int*)d_in[25];
  float* out = (float*)d_out;
  unsigned short* wsb = (unsigned short*)d_ws;

  hipLaunchKernelGGL(prep_kernel, dim3(256), dim3(256), 0, stream,
                     xW, oW, mW, aiW, Ap, wsb);

  const int B = in_sizes[0] / 13;  // 1024
  hipLaunchKernelGGL(Mamba4CTRV3_kernel, dim3(B), dim3(256), 0, stream,
                     dense_x, dense_W, dense_b, tbl, cls, ng, nb, xb, Dp, ob, mb,
                     aib, aoW, aob, w1, b1, w2, b2, w3, b3, sidx, wsb, out);
}

// Round 7
// 298.655 us; speedup vs baseline: 1.0174x; 1.0174x over previous
//
#include <hip/hip_runtime.h>

#define DEV static __device__ __forceinline__

typedef __attribute__((ext_vector_type(8))) short bf16x8;
typedef __attribute__((ext_vector_type(4))) float f32x4;

#define MFMA(a, b, c) __builtin_amdgcn_mfma_f32_16x16x32_bf16(a, b, c, 0, 0, 0)

DEV float bf2f(unsigned short h) { return __uint_as_float(((unsigned)h) << 16); }
DEV unsigned short f2bf(float f) {
  unsigned u = __float_as_uint(f);
  u += 0x7fffu + ((u >> 16) & 1u);
  return (unsigned short)(u >> 16);
}
DEV bf16x8 ld8(const unsigned short* p) { return *(const bf16x8*)p; }

// chunked streaming dot: x in LDS (broadcast), weights streamed from global.
// ~10 live registers (vs 64 for a cached row) -> no spill pressure in the tail.
DEV float dotg64(const float* x, const float* wrow) {
  const float4* wp = (const float4*)wrow;
  float a0 = 0.f, a1 = 0.f;
  #pragma unroll
  for (int c = 0; c < 8; ++c) {
    float4 u = wp[2*c], v = wp[2*c + 1];
    a0 = fmaf(u.x, x[8*c+0], a0); a0 = fmaf(u.y, x[8*c+1], a0);
    a0 = fmaf(u.z, x[8*c+2], a0); a0 = fmaf(u.w, x[8*c+3], a0);
    a1 = fmaf(v.x, x[8*c+4], a1); a1 = fmaf(v.y, x[8*c+5], a1);
    a1 = fmaf(v.z, x[8*c+6], a1); a1 = fmaf(v.w, x[8*c+7], a1);
  }
  return a0 + a1;
}
DEV float wred64(float v) {
  #pragma unroll
  for (int o = 32; o > 0; o >>= 1) v += __shfl_xor(v, o, 64);
  return v;
}

// d_ws layout (ushort element offsets): weights as bf16 hi/lo pairs
#define XW_HI 0        // 4*2*128*64 = 65536
#define XW_LO 65536
#define OW_HI 131072   // 4*2*64*64 = 32768
#define OW_LO 163840
#define MW_HI 196608   // 4*64*128 = 32768
#define MW_LO 229376
#define AI_HI 262144   // 192*64 = 12288
#define AI_LO 274432
#define SC_OFF 286720  // f32 region: 8*256 gate-poly coefs

#define SF 68  // f32 seq row stride (272 B: 16B-aligned, 2-way banks = free)
#define SB 72  // bf16 row stride (144 B: 16B-aligned for ds_read_b128)

__global__ void prep_kernel(const float* __restrict__ xW, const float* __restrict__ oW,
                            const float* __restrict__ mW, const float* __restrict__ aiW,
                            const float* __restrict__ Ap, unsigned short* __restrict__ wsb) {
  const int gid = blockIdx.x * blockDim.x + threadIdx.x;
  const int stride = gridDim.x * blockDim.x;
  for (int i = gid; i < 65536; i += stride) {
    float x = xW[i]; unsigned short h = f2bf(x);
    wsb[XW_HI + i] = h; wsb[XW_LO + i] = f2bf(x - bf2f(h));
  }
  for (int i = gid; i < 32768; i += stride) {
    float x = oW[i]; unsigned short h = f2bf(x);
    wsb[OW_HI + i] = h; wsb[OW_LO + i] = f2bf(x - bf2f(h));
  }
  for (int i = gid; i < 32768; i += stride) {
    float x = mW[i]; unsigned short h = f2bf(x);
    wsb[MW_HI + i] = h; wsb[MW_LO + i] = f2bf(x - bf2f(h));
  }
  for (int i = gid; i < 12288; i += stride) {
    float x = aiW[i]; unsigned short h = f2bf(x);
    wsb[AI_HI + i] = h; wsb[AI_LO + i] = f2bf(x - bf2f(h));
  }
  float* sc = (float*)(wsb + SC_OFF);
  for (int i = gid; i < 512; i += stride) {
    int pi = i >> 6, d = i & 63;
    const float* a = Ap + (size_t)i * 16;
    float s1 = 0, s2 = 0, s3 = 0, s4 = 0;
    #pragma unroll
    for (int n = 0; n < 16; ++n) {
      float z = a[n]; float z2 = z * z;
      s1 += z; s2 += z2; s3 += z2 * z; s4 += z2 * z2;
    }
    sc[pi*256 + d]       = s1;
    sc[pi*256 + 64 + d]  = s2 * 0.5f;
    sc[pi*256 + 128 + d] = s3 * (1.f/6.f);
    sc[pi*256 + 192 + d] = s4 * (1.f/24.f);
  }
}

// B=1024, ND=13, NS=26, V=10000, D=64, H=8, N=16, NL=4, SEQ=40
// launch_bounds arg=3 -> VGPR cap 84. R6 lesson: any per-thread array that
// lives across a barrier spills at this cap (h[20] cost ~42 MB scratch
// writes). This version has NO barrier-crossing arrays: the scan recomputes
// its prefix (two-pass), the tail streams weights chunk-wise.
__global__ __launch_bounds__(256, 3)
void Mamba4CTRV3_kernel(
    const float* __restrict__ dense_x, const float* __restrict__ dense_W,
    const float* __restrict__ dense_b, const float* __restrict__ tbl,
    const float* __restrict__ cls, const float* __restrict__ ng,
    const float* __restrict__ nb, const float* __restrict__ xb,
    const float* __restrict__ Dp, const float* __restrict__ ob,
    const float* __restrict__ mb, const float* __restrict__ aib,
    const float* __restrict__ aoW, const float* __restrict__ aob,
    const float* __restrict__ w1, const float* __restrict__ b1,
    const float* __restrict__ w2, const float* __restrict__ b2,
    const float* __restrict__ w3, const float* __restrict__ b3,
    const int* __restrict__ sidx, const unsigned short* __restrict__ wsb,
    float* __restrict__ out) {
  // LDS 40,832 B -> 4 blocks/CU cap (163,840/4 = 40,960).
  __shared__ __align__(16) unsigned char smem[40832];
  float*          s_seq  = (float*)smem;                     // 40xSF f32 residual spine
  unsigned short* s_xnb  = (unsigned short*)(smem + 10880);  // 40xSB bf16 xn / final seq
  unsigned short* bG0    = (unsigned short*)(smem + 16640);  // gate0 -> out0 ; tail f32 scratch A
  unsigned short* bG1    = (unsigned short*)(smem + 22400);  // gate1 -> out1 ; tail f32 scratch B
  unsigned short* bB0    = (unsigned short*)(smem + 28160);  // Bm0 -> f-branch ; tail: K bf16
  unsigned short* bB1    = (unsigned short*)(smem + 33920);  // Bm1 -> r-branch ; tail: V bf16
  float*          s_small= (float*)(smem + 39680);           // 256 f32 (seg totals; ph0 dx/idx)
  float* g0f = (float*)bG0;
  float* g1f = (float*)bG1;
  const float* scf = (const float*)(wsb + SC_OFF);

  const int tid = threadIdx.x, b = blockIdx.x;
  const int lane = tid & 63, wv = tid >> 6;
  const int arow = lane & 15;      // A-frag row / C-frag col
  const int aq = (lane >> 4) * 8;  // A-frag k offset
  const int rq = (lane >> 4) * 4;  // C-frag row base

  // ---------------- Phase 0: build seq (f32) ----------------
  {
    float* s_dx = s_small;
    int* s_idx = (int*)(s_small + 16);
    if (tid < 13) s_dx[tid] = dense_x[b*13 + tid];
    if (tid >= 64 && tid < 90) {
      int s = tid - 64;
      int v = sidx[b*26 + s];
      v = v < 0 ? 0 : (v > 10000 ? 10000 : v);
      s_idx[s] = v;
    }
    __syncthreads();
    if (tid < 64) s_seq[tid] = cls[tid];
    {
      float x[13];
      #pragma unroll
      for (int k = 0; k < 13; ++k) x[k] = s_dx[k];
      for (int j = tid; j < 832; j += 256) {
        float acc = dense_b[j];
        #pragma unroll
        for (int k = 0; k < 13; ++k) acc = fmaf(x[k], dense_W[j*13 + k], acc);
        s_seq[(1 + (j >> 6)) * SF + (j & 63)] = acc;
      }
    }
    for (int e = tid; e < 26*16; e += 256) {
      int s = e >> 4, c = e & 15;
      const float4* row = (const float4*)(tbl + ((size_t)(s*10001 + s_idx[s]))*64);
      ((float4*)&s_seq[(14 + s) * SF])[c] = row[c];
    }
  }
  __syncthreads();

  // ---------------- 4 bidirectional mamba layers (dirs fused) ----------------
  for (int L = 0; L < 4; ++L) {
    const int pi0 = 2*L, pi1 = 2*L + 1;

    // LN once per layer (shared by both directions)
    {
      const int half = lane >> 5, dl = lane & 31;
      for (int it = 0; it < 5; ++it) {
        int t = wv*10 + it*2 + half;
        int e = t*SF + dl;
        float x0 = s_seq[e], x1 = s_seq[e + 32];
        float s = x0 + x1, q = fmaf(x0, x0, x1*x1);
        #pragma unroll
        for (int o = 16; o > 0; o >>= 1) { s += __shfl_xor(s, o, 64); q += __shfl_xor(q, o, 64); }
        float mean = s * (1.f/64.f);
        float var = q * (1.f/64.f) - mean*mean;
        float rs = rsqrtf(var + 1e-5f);
        float xn0 = fmaf((x0 - mean) * rs, ng[pi0*64 + dl], nb[pi0*64 + dl]);
        float xn1 = fmaf((x1 - mean) * rs, ng[pi0*64 + dl + 32], nb[pi0*64 + dl + 32]);
        int eb = t*SB + dl;
        s_xnb[eb] = f2bf(xn0); s_xnb[eb + 32] = f2bf(xn1);
      }
    }
    __syncthreads();

    // xproj both dirs: pass0 = delta cols (0..63), pass1 = Bm cols (64..127)
    #pragma unroll 1
    for (int p = 0; p < 2; ++p) {
      const int j = (wv + 4*p)*16 + arow;
      const unsigned short* Wh0 = wsb + XW_HI + pi0*8192 + j*64;
      const unsigned short* Wl0 = wsb + XW_LO + pi0*8192 + j*64;
      const unsigned short* Wh1 = wsb + XW_HI + pi1*8192 + j*64;
      const unsigned short* Wl1 = wsb + XW_LO + pi1*8192 + j*64;
      bf16x8 bh00 = ld8(Wh0 + aq), bh01 = ld8(Wh0 + 32 + aq);
      bf16x8 bl00 = ld8(Wl0 + aq), bl01 = ld8(Wl0 + 32 + aq);
      bf16x8 bh10 = ld8(Wh1 + aq), bh11 = ld8(Wh1 + 32 + aq);
      bf16x8 bl10 = ld8(Wl1 + aq), bl11 = ld8(Wl1 + 32 + aq);
      const float bj0 = xb[pi0*128 + j], bj1 = xb[pi1*128 + j];
      float c10=0,c20=0,c30=0,c40=0,c11=0,c21=0,c31=0,c41=0;
      if (p == 0) {
        c10=scf[pi0*256+j]; c20=scf[pi0*256+64+j]; c30=scf[pi0*256+128+j]; c40=scf[pi0*256+192+j];
        c11=scf[pi1*256+j]; c21=scf[pi1*256+64+j]; c31=scf[pi1*256+128+j]; c41=scf[pi1*256+192+j];
      }
      for (int mt = 0; mt < 3; ++mt) {
        const unsigned short* A = s_xnb + (mt*16 + arow)*SB + aq;
        bf16x8 ah0 = ld8(A), ah1 = ld8(A + 32);
        f32x4 a0 = {0,0,0,0}, a1 = {0,0,0,0};
        a0 = MFMA(ah0, bh00, a0); a0 = MFMA(ah0, bl00, a0);
        a0 = MFMA(ah1, bh01, a0); a0 = MFMA(ah1, bl01, a0);
        a1 = MFMA(ah0, bh10, a1); a1 = MFMA(ah0, bl10, a1);
        a1 = MFMA(ah1, bh11, a1); a1 = MFMA(ah1, bl11, a1);
        const int rbase = mt*16 + rq;
        #pragma unroll
        for (int r = 0; r < 4; ++r) {
          int row = rbase + r;
          if (row >= 40) break;
          float x0v = a0[r] + bj0, x1v = a1[r] + bj1;
          if (p == 0) {  // delta -> gate deviation (bf16)
            float sp0 = fmaxf(x0v, 0.f) + __logf(1.f + __expf(-fabsf(x0v)));
            float sp1 = fmaxf(x1v, 0.f) + __logf(1.f + __expf(-fabsf(x1v)));
            bG0[row*SB + j] = f2bf(sp0 * fmaf(sp0, fmaf(sp0, fmaf(sp0, c40, c30), c20), c10));
            bG1[row*SB + j] = f2bf(sp1 * fmaf(sp1, fmaf(sp1, fmaf(sp1, c41, c31), c21), c11));
          } else {       // raw Bm (bf16)
            int d = j - 64;
            bB0[row*SB + d] = f2bf(x0v);
            bB1[row*SB + d] = f2bf(x1v);
          }
        }
      }
    }
    __syncthreads();

    // Scan, two-pass recompute (NO barrier-crossing arrays -> no spill).
    // Work item = (seg, dir, d): 2*2*64 = 256, one per thread.
    {
      const int d = tid & 63, dir = (tid >> 6) & 1, seg = tid >> 7;
      const unsigned short* bmb = dir ? bB1 : bB0;
      // Da: segment total only
      float run = 0.f;
      #pragma unroll
      for (int k = 0; k < 20; ++k) {
        int t = dir ? (39 - (seg*20 + k)) : (seg*20 + k);
        run = fmaf(bf2f(s_xnb[t*SB + d]), bf2f(bmb[t*SB + d]), run);
      }
      s_small[seg*128 + dir*64 + d] = run;
      __syncthreads();
      // Db: recompute prefix with carry, gate, write out (in-place over gate)
      unsigned short* gb = dir ? bG1 : bG0;
      const float off = seg ? s_small[dir*64 + d] : 0.f;
      const float dpd = Dp[(2*L + dir)*64 + d];
      run = off;
      #pragma unroll
      for (int k = 0; k < 20; ++k) {
        int t = dir ? (39 - (seg*20 + k)) : (seg*20 + k);
        float xn = bf2f(s_xnb[t*SB + d]);
        run = fmaf(xn, bf2f(bmb[t*SB + d]), run);
        float gate = 16.f + bf2f(gb[t*SB + d]);
        gb[t*SB + d] = f2bf(fmaf(run, gate, xn * dpd));
      }
    }
    __syncthreads();

    // outproj both dirs + residual -> bB0 (fwd) / bB1 (rev), bf16
    {
      const int j = wv*16 + arow;
      const unsigned short* Wh0 = wsb + OW_HI + pi0*4096 + j*64;
      const unsigned short* Wl0 = wsb + OW_LO + pi0*4096 + j*64;
      const unsigned short* Wh1 = wsb + OW_HI + pi1*4096 + j*64;
      const unsigned short* Wl1 = wsb + OW_LO + pi1*4096 + j*64;
      bf16x8 bh00 = ld8(Wh0 + aq), bh01 = ld8(Wh0 + 32 + aq);
      bf16x8 bl00 = ld8(Wl0 + aq), bl01 = ld8(Wl0 + 32 + aq);
      bf16x8 bh10 = ld8(Wh1 + aq), bh11 = ld8(Wh1 + 32 + aq);
      bf16x8 bl10 = ld8(Wl1 + aq), bl11 = ld8(Wl1 + 32 + aq);
      const float bo0 = ob[pi0*64 + j], bo1 = ob[pi1*64 + j];
      for (int mt = 0; mt < 3; ++mt) {
        const unsigned short* A0 = bG0 + (mt*16 + arow)*SB + aq;
        const unsigned short* A1 = bG1 + (mt*16 + arow)*SB + aq;
        bf16x8 a00 = ld8(A0), a01 = ld8(A0 + 32);
        bf16x8 a10 = ld8(A1), a11 = ld8(A1 + 32);
        f32x4 c0 = {0,0,0,0}, c1 = {0,0,0,0};
        c0 = MFMA(a00, bh00, c0); c0 = MFMA(a00, bl00, c0);
        c0 = MFMA(a01, bh01, c0); c0 = MFMA(a01, bl01, c0);
        c1 = MFMA(a10, bh10, c1); c1 = MFMA(a10, bl10, c1);
        c1 = MFMA(a11, bh11, c1); c1 = MFMA(a11, bl11, c1);
        const int rbase = mt*16 + rq;
        #pragma unroll
        for (int r = 0; r < 4; ++r) {
          int row = rbase + r;
          if (row >= 40) break;
          float res = s_seq[row*SF + j];
          bB0[row*SB + j] = f2bf(c0[r] + bo0 + res);
          bB1[row*SB + j] = f2bf(c1[r] + bo1 + res);
        }
      }
    }
    __syncthreads();

    // merge: seq = [f, r] @ mW.T + mb -> s_seq f32 (+ s_xnb bf16 after last layer)
    {
      const int n0 = wv*16 + arow;
      const unsigned short* Wh = wsb + MW_HI + L*8192 + n0*128;
      const unsigned short* Wl = wsb + MW_LO + L*8192 + n0*128;
      bf16x8 bh[4], bl[4];
      #pragma unroll
      for (int ks = 0; ks < 4; ++ks) { bh[ks] = ld8(Wh + ks*32 + aq); bl[ks] = ld8(Wl + ks*32 + aq); }
      const float bo = mb[L*64 + n0];
      for (int mt = 0; mt < 3; ++mt) {
        const unsigned short* Af = bB0 + (mt*16 + arow)*SB + aq;
        const unsigned short* Ar = bB1 + (mt*16 + arow)*SB + aq;
        bf16x8 fh0 = ld8(Af), fh1 = ld8(Af + 32);
        bf16x8 rh0 = ld8(Ar), rh1 = ld8(Ar + 32);
        f32x4 a0 = {0,0,0,0};
        a0 = MFMA(fh0, bh[0], a0); a0 = MFMA(fh0, bl[0], a0);
        a0 = MFMA(fh1, bh[1], a0); a0 = MFMA(fh1, bl[1], a0);
        a0 = MFMA(rh0, bh[2], a0); a0 = MFMA(rh0, bl[2], a0);
        a0 = MFMA(rh1, bh[3], a0); a0 = MFMA(rh1, bl[3], a0);
        const int rbase = mt*16 + rq;
        #pragma unroll
        for (int r = 0; r < 4; ++r) {
          int row = rbase + r;
          if (row >= 40) break;
          float v = a0[r] + bo;
          s_seq[row*SF + n0] = v;
          if (L == 3) s_xnb[row*SB + n0] = f2bf(v);
        }
      }
    }
    __syncthreads();
  }

  // ---------------- Attention tail (token 0 only consumed downstream) ----------------
  // QKV, balanced: 28 (col-tile, mt) units round-robin over 4 waves.
  // q(row0) -> g0f[320..384), K bf16 -> bB0, V bf16 -> bB1, c=seq0 -> g0f[384..448)
  {
    #pragma unroll 1
    for (int i = 0; i < 7; ++i) {
      const int u = wv + 4*i;
      int jt, mt;
      if (u < 4) { jt = u; mt = 0; }
      else { int v = u - 4; jt = 4 + (v & 7); mt = v >> 3; }
      const int j = jt*16 + arow;
      const unsigned short* Wh = wsb + AI_HI + j*64;
      const unsigned short* Wl = wsb + AI_LO + j*64;
      bf16x8 bh0 = ld8(Wh + aq), bh1 = ld8(Wh + 32 + aq);
      bf16x8 bl0 = ld8(Wl + aq), bl1 = ld8(Wl + 32 + aq);
      const float bj = aib[j];
      const unsigned short* A = s_xnb + (mt*16 + arow)*SB + aq;
      bf16x8 ah0 = ld8(A), ah1 = ld8(A + 32);
      f32x4 a0 = {0,0,0,0};
      a0 = MFMA(ah0, bh0, a0); a0 = MFMA(ah0, bl0, a0);
      a0 = MFMA(ah1, bh1, a0); a0 = MFMA(ah1, bl1, a0);
      const int rbase = mt*16 + rq;
      #pragma unroll
      for (int r = 0; r < 4; ++r) {
        int row = rbase + r;
        if (row >= 40) break;
        float val = a0[r] + bj;
        if (jt < 4) { if (row == 0) g0f[320 + j] = val; }
        else if (jt < 8) bB0[row*SB + (j - 64)] = f2bf(val);
        else bB1[row*SB + (j - 128)] = f2bf(val);
      }
    }
    if (tid >= 192) g0f[384 + (tid - 192)] = s_seq[tid - 192];
  }
  __syncthreads();

  // logits (8 heads x 40 keys) -> g0f[0..320)
  for (int e = tid; e < 320; e += 256) {
    int h = e / 40, kk = e - h*40;
    float acc = 0.f;
    #pragma unroll
    for (int i = 0; i < 8; ++i)
      acc += g0f[320 + h*8 + i] * bf2f(bB0[kk*SB + h*8 + i]);
    g0f[e] = acc * 0.35355339059327373f;
  }
  __syncthreads();

  // softmax: 2 heads per wave, 32 lanes per head
  {
    const int h = wv*2 + (lane >> 5), jl = lane & 31;
    float a = g0f[h*40 + jl];
    float bv = (jl < 8) ? g0f[h*40 + 32 + jl] : -1e30f;
    float m = fmaxf(a, bv);
    #pragma unroll
    for (int o = 16; o > 0; o >>= 1) m = fmaxf(m, __shfl_xor(m, o, 32));
    float pa = __expf(a - m), pb = (jl < 8) ? __expf(bv - m) : 0.f;
    float s = pa + pb;
    #pragma unroll
    for (int o = 16; o > 0; o >>= 1) s += __shfl_xor(s, o, 32);
    float inv = 1.f / s;
    g0f[h*40 + jl] = pa * inv;
    if (jl < 8) g0f[h*40 + 32 + jl] = pb * inv;
  }
  __syncthreads();

  // ao partials over 256 threads -> g1f[0..256)
  {
    const int d = tid & 63, qrt = tid >> 6, hh = d >> 3;
    float acc = 0.f;
    #pragma unroll
    for (int k = qrt*10; k < qrt*10 + 10; ++k)
      acc += g0f[hh*40 + k] * bf2f(bB1[k*SB + d]);
    g1f[qrt*64 + d] = acc;
  }
  __syncthreads();
  if (tid < 64) g1f[256 + tid] = g1f[tid] + g1f[64 + tid] + g1f[128 + tid] + g1f[192 + tid];
  __syncthreads();

  // c = seq0 + ao @ aoW.T + aob -> g0f[448..512)
  if (tid < 64)
    g0f[448 + tid] = g0f[384 + tid] + aob[tid] + dotg64(&g1f[256], aoW + (size_t)tid*64);
  __syncthreads();

  // MLP1 -> g1f[320..448)
  if (tid < 128)
    g1f[320 + tid] = fmaxf(b1[tid] + dotg64(&g0f[448], w1 + (size_t)tid*64), 0.f);
  __syncthreads();

  // MLP2 -> g1f[448..512)
  if (tid < 64) {
    float acc = dotg64(&g1f[320], w2 + (size_t)tid*128)
              + dotg64(&g1f[384], w2 + (size_t)tid*128 + 64);
    g1f[448 + tid] = fmaxf(acc + b2[tid], 0.f);
  }
  __syncthreads();

  if (tid < 64) {
    float v = g1f[448 + tid] * w3[tid];
    v = wred64(v);
    if (tid == 0) out[b] = v + b3[0];
  }
}

extern "C" void kernel_launch(void* const* d_in, const int* in_sizes, int n_in,
                              void* d_out, int out_size, void* d_ws, size_t ws_size,
                              hipStream_t stream) {
  (void)n_in; (void)ws_size; (void)out_size;
  const float* dense_x = (const float*)d_in[0];
  const float* dense_W = (const float*)d_in[1];
  const float* dense_b = (const float*)d_in[2];
  const float* tbl     = (const float*)d_in[3];
  const float* cls     = (const float*)d_in[4];
  const float* ng      = (const float*)d_in[5];
  const float* nb      = (const float*)d_in[6];
  const float* xW      = (const float*)d_in[7];
  const float* xb      = (const float*)d_in[8];
  const float* Ap      = (const float*)d_in[9];
  const float* Dp      = (const float*)d_in[10];
  const float* oW      = (const float*)d_in[11];
  const float* ob      = (const float*)d_in[12];
  const float* mW      = (const float*)d_in[13];
  const float* mb      = (const float*)d_in[14];
  const float* aiW     = (const float*)d_in[15];
  const float* aib     = (const float*)d_in[16];
  const float* aoW     = (const float*)d_in[17];
  const float* aob     = (const float*)d_in[18];
  const float* w1      = (const float*)d_in[19];
  const float* b1      = (const float*)d_in[20];
  const float* w2      = (const float*)d_in[21];
  const float* b2      = (const float*)d_in[22];
  const float* w3      = (const float*)d_in[23];
  const float* b3      = (const float*)d_in[24];
  const int*   sidx    = (const int*)d_in[25];
  float* out = (float*)d_out;
  unsigned short* wsb = (unsigned short*)d_ws;

  hipLaunchKernelGGL(prep_kernel, dim3(256), dim3(256), 0, stream,
                     xW, oW, mW, aiW, Ap, wsb);

  const int B = in_sizes[0] / 13;  // 1024
  hipLaunchKernelGGL(Mamba4CTRV3_kernel, dim3(B), dim3(256), 0, stream,
                     dense_x, dense_W, dense_b, tbl, cls, ng, nb, xb, Dp, ob, mb,
                     aib, aoW, aob, w1, b1, w2, b2, w3, b3, sidx, wsb, out);
}

// Round 8
// 278.293 us; speedup vs baseline: 1.0919x; 1.0732x over previous
//
#include <hip/hip_runtime.h>

#define DEV static __device__ __forceinline__

typedef __attribute__((ext_vector_type(8))) short bf16x8;
typedef __attribute__((ext_vector_type(4))) float f32x4;

#define MFMA(a, b, c) __builtin_amdgcn_mfma_f32_16x16x32_bf16(a, b, c, 0, 0, 0)

DEV float bf2f(unsigned short h) { return __uint_as_float(((unsigned)h) << 16); }
DEV unsigned short f2bf(float f) {
  unsigned u = __float_as_uint(f);
  u += 0x7fffu + ((u >> 16) & 1u);
  return (unsigned short)(u >> 16);
}
DEV bf16x8 ld8(const unsigned short* p) { return *(const bf16x8*)p; }

// chunked streaming dot: x in LDS (broadcast), weights streamed from global.
DEV float dotg64(const float* x, const float* wrow) {
  const float4* wp = (const float4*)wrow;
  float a0 = 0.f, a1 = 0.f;
  #pragma unroll
  for (int c = 0; c < 8; ++c) {
    float4 u = wp[2*c], v = wp[2*c + 1];
    a0 = fmaf(u.x, x[8*c+0], a0); a0 = fmaf(u.y, x[8*c+1], a0);
    a0 = fmaf(u.z, x[8*c+2], a0); a0 = fmaf(u.w, x[8*c+3], a0);
    a1 = fmaf(v.x, x[8*c+4], a1); a1 = fmaf(v.y, x[8*c+5], a1);
    a1 = fmaf(v.z, x[8*c+6], a1); a1 = fmaf(v.w, x[8*c+7], a1);
  }
  return a0 + a1;
}
DEV float wred64(float v) {
  #pragma unroll
  for (int o = 32; o > 0; o >>= 1) v += __shfl_xor(v, o, 64);
  return v;
}

// d_ws layout (ushort element offsets): weights as bf16 hi/lo pairs
#define XW_HI 0        // 4*2*128*64 = 65536
#define XW_LO 65536
#define OW_HI 131072   // 4*2*64*64 = 32768
#define OW_LO 163840
#define MW_HI 196608   // 4*64*128 = 32768
#define MW_LO 229376
#define AI_HI 262144   // 192*64 = 12288
#define AI_LO 274432
#define SC_OFF 286720  // f32 region: 8*256 gate-poly coefs

#define SF 68  // f32 seq row stride
#define SB 72  // bf16 row stride (16B-aligned rows for ds_read_b128)

__global__ void prep_kernel(const float* __restrict__ xW, const float* __restrict__ oW,
                            const float* __restrict__ mW, const float* __restrict__ aiW,
                            const float* __restrict__ Ap, unsigned short* __restrict__ wsb) {
  const int gid = blockIdx.x * blockDim.x + threadIdx.x;
  const int stride = gridDim.x * blockDim.x;
  for (int i = gid; i < 65536; i += stride) {
    float x = xW[i]; unsigned short h = f2bf(x);
    wsb[XW_HI + i] = h; wsb[XW_LO + i] = f2bf(x - bf2f(h));
  }
  for (int i = gid; i < 32768; i += stride) {
    float x = oW[i]; unsigned short h = f2bf(x);
    wsb[OW_HI + i] = h; wsb[OW_LO + i] = f2bf(x - bf2f(h));
  }
  for (int i = gid; i < 32768; i += stride) {
    float x = mW[i]; unsigned short h = f2bf(x);
    wsb[MW_HI + i] = h; wsb[MW_LO + i] = f2bf(x - bf2f(h));
  }
  for (int i = gid; i < 12288; i += stride) {
    float x = aiW[i]; unsigned short h = f2bf(x);
    wsb[AI_HI + i] = h; wsb[AI_LO + i] = f2bf(x - bf2f(h));
  }
  float* sc = (float*)(wsb + SC_OFF);
  for (int i = gid; i < 512; i += stride) {
    int pi = i >> 6, d = i & 63;
    const float* a = Ap + (size_t)i * 16;
    float s1 = 0, s2 = 0, s3 = 0, s4 = 0;
    #pragma unroll
    for (int n = 0; n < 16; ++n) {
      float z = a[n]; float z2 = z * z;
      s1 += z; s2 += z2; s3 += z2 * z; s4 += z2 * z2;
    }
    sc[pi*256 + d]       = s1;
    sc[pi*256 + 64 + d]  = s2 * 0.5f;
    sc[pi*256 + 128 + d] = s3 * (1.f/6.f);
    sc[pi*256 + 192 + d] = s4 * (1.f/24.f);
  }
}

// B=1024, ND=13, NS=26, V=10000, D=64, H=8, N=16, NL=4, SEQ=40
// launch_bounds arg history (cap ~= 256/arg): arg2->128 regs, arg3->84, arg4->64.
// R7 at 84: fused-dirs phases hold ~80 live regs -> per-phase spill (~28 MB
// scratch writes/dispatch, occupancy pinned 23%). arg2 -> cap 128: spill-free
// AND still 4 waves/SIMD (512-reg pool), so the 40,832 B LDS remains the
// 4-blocks/CU limiter.
__global__ __launch_bounds__(256, 2)
void Mamba4CTRV3_kernel(
    const float* __restrict__ dense_x, const float* __restrict__ dense_W,
    const float* __restrict__ dense_b, const float* __restrict__ tbl,
    const float* __restrict__ cls, const float* __restrict__ ng,
    const float* __restrict__ nb, const float* __restrict__ xb,
    const float* __restrict__ Dp, const float* __restrict__ ob,
    const float* __restrict__ mb, const float* __restrict__ aib,
    const float* __restrict__ aoW, const float* __restrict__ aob,
    const float* __restrict__ w1, const float* __restrict__ b1,
    const float* __restrict__ w2, const float* __restrict__ b2,
    const float* __restrict__ w3, const float* __restrict__ b3,
    const int* __restrict__ sidx, const unsigned short* __restrict__ wsb,
    float* __restrict__ out) {
  // LDS 40,832 B -> 4 blocks/CU cap (163,840/4 = 40,960).
  __shared__ __align__(16) unsigned char smem[40832];
  float*          s_seq  = (float*)smem;                     // 40xSF f32 residual spine
  unsigned short* s_xnb  = (unsigned short*)(smem + 10880);  // 40xSB bf16 xn / final seq
  unsigned short* bG0    = (unsigned short*)(smem + 16640);  // gate0 -> out0 ; tail f32 scratch A
  unsigned short* bG1    = (unsigned short*)(smem + 22400);  // gate1 -> out1 ; tail f32 scratch B
  unsigned short* bB0    = (unsigned short*)(smem + 28160);  // Bm0 -> f-branch ; tail: K bf16
  unsigned short* bB1    = (unsigned short*)(smem + 33920);  // Bm1 -> r-branch ; tail: V bf16
  float*          s_small= (float*)(smem + 39680);           // 256 f32 (seg totals; ph0 dx/idx)
  float* g0f = (float*)bG0;
  float* g1f = (float*)bG1;
  const float* scf = (const float*)(wsb + SC_OFF);

  const int tid = threadIdx.x, b = blockIdx.x;
  const int lane = tid & 63, wv = tid >> 6;
  const int arow = lane & 15;      // A-frag row / C-frag col
  const int aq = (lane >> 4) * 8;  // A-frag k offset
  const int rq = (lane >> 4) * 4;  // C-frag row base

  // ---------------- Phase 0: build seq (f32) ----------------
  {
    float* s_dx = s_small;
    int* s_idx = (int*)(s_small + 16);
    if (tid < 13) s_dx[tid] = dense_x[b*13 + tid];
    if (tid >= 64 && tid < 90) {
      int s = tid - 64;
      int v = sidx[b*26 + s];
      v = v < 0 ? 0 : (v > 10000 ? 10000 : v);
      s_idx[s] = v;
    }
    __syncthreads();
    if (tid < 64) s_seq[tid] = cls[tid];
    {
      float x[13];
      #pragma unroll
      for (int k = 0; k < 13; ++k) x[k] = s_dx[k];
      for (int j = tid; j < 832; j += 256) {
        float acc = dense_b[j];
        #pragma unroll
        for (int k = 0; k < 13; ++k) acc = fmaf(x[k], dense_W[j*13 + k], acc);
        s_seq[(1 + (j >> 6)) * SF + (j & 63)] = acc;
      }
    }
    for (int e = tid; e < 26*16; e += 256) {
      int s = e >> 4, c = e & 15;
      const float4* row = (const float4*)(tbl + ((size_t)(s*10001 + s_idx[s]))*64);
      ((float4*)&s_seq[(14 + s) * SF])[c] = row[c];
    }
  }
  __syncthreads();

  // ---------------- 4 bidirectional mamba layers (dirs fused) ----------------
  for (int L = 0; L < 4; ++L) {
    const int pi0 = 2*L, pi1 = 2*L + 1;

    // LN once per layer (shared by both directions)
    {
      const int half = lane >> 5, dl = lane & 31;
      for (int it = 0; it < 5; ++it) {
        int t = wv*10 + it*2 + half;
        int e = t*SF + dl;
        float x0 = s_seq[e], x1 = s_seq[e + 32];
        float s = x0 + x1, q = fmaf(x0, x0, x1*x1);
        #pragma unroll
        for (int o = 16; o > 0; o >>= 1) { s += __shfl_xor(s, o, 64); q += __shfl_xor(q, o, 64); }
        float mean = s * (1.f/64.f);
        float var = q * (1.f/64.f) - mean*mean;
        float rs = rsqrtf(var + 1e-5f);
        float xn0 = fmaf((x0 - mean) * rs, ng[pi0*64 + dl], nb[pi0*64 + dl]);
        float xn1 = fmaf((x1 - mean) * rs, ng[pi0*64 + dl + 32], nb[pi0*64 + dl + 32]);
        int eb = t*SB + dl;
        s_xnb[eb] = f2bf(xn0); s_xnb[eb + 32] = f2bf(xn1);
      }
    }
    __syncthreads();

    // xproj both dirs: pass0 = delta cols (0..63), pass1 = Bm cols (64..127)
    #pragma unroll 1
    for (int p = 0; p < 2; ++p) {
      const int j = (wv + 4*p)*16 + arow;
      const unsigned short* Wh0 = wsb + XW_HI + pi0*8192 + j*64;
      const unsigned short* Wl0 = wsb + XW_LO + pi0*8192 + j*64;
      const unsigned short* Wh1 = wsb + XW_HI + pi1*8192 + j*64;
      const unsigned short* Wl1 = wsb + XW_LO + pi1*8192 + j*64;
      bf16x8 bh00 = ld8(Wh0 + aq), bh01 = ld8(Wh0 + 32 + aq);
      bf16x8 bl00 = ld8(Wl0 + aq), bl01 = ld8(Wl0 + 32 + aq);
      bf16x8 bh10 = ld8(Wh1 + aq), bh11 = ld8(Wh1 + 32 + aq);
      bf16x8 bl10 = ld8(Wl1 + aq), bl11 = ld8(Wl1 + 32 + aq);
      const float bj0 = xb[pi0*128 + j], bj1 = xb[pi1*128 + j];
      float c10=0,c20=0,c30=0,c40=0,c11=0,c21=0,c31=0,c41=0;
      if (p == 0) {
        c10=scf[pi0*256+j]; c20=scf[pi0*256+64+j]; c30=scf[pi0*256+128+j]; c40=scf[pi0*256+192+j];
        c11=scf[pi1*256+j]; c21=scf[pi1*256+64+j]; c31=scf[pi1*256+128+j]; c41=scf[pi1*256+192+j];
      }
      for (int mt = 0; mt < 3; ++mt) {
        const unsigned short* A = s_xnb + (mt*16 + arow)*SB + aq;
        bf16x8 ah0 = ld8(A), ah1 = ld8(A + 32);
        f32x4 a0 = {0,0,0,0}, a1 = {0,0,0,0};
        a0 = MFMA(ah0, bh00, a0); a0 = MFMA(ah0, bl00, a0);
        a0 = MFMA(ah1, bh01, a0); a0 = MFMA(ah1, bl01, a0);
        a1 = MFMA(ah0, bh10, a1); a1 = MFMA(ah0, bl10, a1);
        a1 = MFMA(ah1, bh11, a1); a1 = MFMA(ah1, bl11, a1);
        const int rbase = mt*16 + rq;
        #pragma unroll
        for (int r = 0; r < 4; ++r) {
          int row = rbase + r;
          if (row >= 40) break;
          float x0v = a0[r] + bj0, x1v = a1[r] + bj1;
          if (p == 0) {  // delta -> gate deviation (bf16)
            float sp0 = fmaxf(x0v, 0.f) + __logf(1.f + __expf(-fabsf(x0v)));
            float sp1 = fmaxf(x1v, 0.f) + __logf(1.f + __expf(-fabsf(x1v)));
            bG0[row*SB + j] = f2bf(sp0 * fmaf(sp0, fmaf(sp0, fmaf(sp0, c40, c30), c20), c10));
            bG1[row*SB + j] = f2bf(sp1 * fmaf(sp1, fmaf(sp1, fmaf(sp1, c41, c31), c21), c11));
          } else {       // raw Bm (bf16)
            int d = j - 64;
            bB0[row*SB + d] = f2bf(x0v);
            bB1[row*SB + d] = f2bf(x1v);
          }
        }
      }
    }
    __syncthreads();

    // Scan, two-pass recompute (no barrier-crossing arrays).
    {
      const int d = tid & 63, dir = (tid >> 6) & 1, seg = tid >> 7;
      const unsigned short* bmb = dir ? bB1 : bB0;
      float run = 0.f;
      #pragma unroll
      for (int k = 0; k < 20; ++k) {
        int t = dir ? (39 - (seg*20 + k)) : (seg*20 + k);
        run = fmaf(bf2f(s_xnb[t*SB + d]), bf2f(bmb[t*SB + d]), run);
      }
      s_small[seg*128 + dir*64 + d] = run;
      __syncthreads();
      unsigned short* gb = dir ? bG1 : bG0;
      const float off = seg ? s_small[dir*64 + d] : 0.f;
      const float dpd = Dp[(2*L + dir)*64 + d];
      run = off;
      #pragma unroll
      for (int k = 0; k < 20; ++k) {
        int t = dir ? (39 - (seg*20 + k)) : (seg*20 + k);
        float xn = bf2f(s_xnb[t*SB + d]);
        run = fmaf(xn, bf2f(bmb[t*SB + d]), run);
        float gate = 16.f + bf2f(gb[t*SB + d]);
        gb[t*SB + d] = f2bf(fmaf(run, gate, xn * dpd));
      }
    }
    __syncthreads();

    // outproj both dirs + residual -> bB0 (fwd) / bB1 (rev), bf16
    {
      const int j = wv*16 + arow;
      const unsigned short* Wh0 = wsb + OW_HI + pi0*4096 + j*64;
      const unsigned short* Wl0 = wsb + OW_LO + pi0*4096 + j*64;
      const unsigned short* Wh1 = wsb + OW_HI + pi1*4096 + j*64;
      const unsigned short* Wl1 = wsb + OW_LO + pi1*4096 + j*64;
      bf16x8 bh00 = ld8(Wh0 + aq), bh01 = ld8(Wh0 + 32 + aq);
      bf16x8 bl00 = ld8(Wl0 + aq), bl01 = ld8(Wl0 + 32 + aq);
      bf16x8 bh10 = ld8(Wh1 + aq), bh11 = ld8(Wh1 + 32 + aq);
      bf16x8 bl10 = ld8(Wl1 + aq), bl11 = ld8(Wl1 + 32 + aq);
      const float bo0 = ob[pi0*64 + j], bo1 = ob[pi1*64 + j];
      for (int mt = 0; mt < 3; ++mt) {
        const unsigned short* A0 = bG0 + (mt*16 + arow)*SB + aq;
        const unsigned short* A1 = bG1 + (mt*16 + arow)*SB + aq;
        bf16x8 a00 = ld8(A0), a01 = ld8(A0 + 32);
        bf16x8 a10 = ld8(A1), a11 = ld8(A1 + 32);
        f32x4 c0 = {0,0,0,0}, c1 = {0,0,0,0};
        c0 = MFMA(a00, bh00, c0); c0 = MFMA(a00, bl00, c0);
        c0 = MFMA(a01, bh01, c0); c0 = MFMA(a01, bl01, c0);
        c1 = MFMA(a10, bh10, c1); c1 = MFMA(a10, bl10, c1);
        c1 = MFMA(a11, bh11, c1); c1 = MFMA(a11, bl11, c1);
        const int rbase = mt*16 + rq;
        #pragma unroll
        for (int r = 0; r < 4; ++r) {
          int row = rbase + r;
          if (row >= 40) break;
          float res = s_seq[row*SF + j];
          bB0[row*SB + j] = f2bf(c0[r] + bo0 + res);
          bB1[row*SB + j] = f2bf(c1[r] + bo1 + res);
        }
      }
    }
    __syncthreads();

    // merge: seq = [f, r] @ mW.T + mb -> s_seq f32 (+ s_xnb bf16 after last layer)
    {
      const int n0 = wv*16 + arow;
      const unsigned short* Wh = wsb + MW_HI + L*8192 + n0*128;
      const unsigned short* Wl = wsb + MW_LO + L*8192 + n0*128;
      bf16x8 bh[4], bl[4];
      #pragma unroll
      for (int ks = 0; ks < 4; ++ks) { bh[ks] = ld8(Wh + ks*32 + aq); bl[ks] = ld8(Wl + ks*32 + aq); }
      const float bo = mb[L*64 + n0];
      for (int mt = 0; mt < 3; ++mt) {
        const unsigned short* Af = bB0 + (mt*16 + arow)*SB + aq;
        const unsigned short* Ar = bB1 + (mt*16 + arow)*SB + aq;
        bf16x8 fh0 = ld8(Af), fh1 = ld8(Af + 32);
        bf16x8 rh0 = ld8(Ar), rh1 = ld8(Ar + 32);
        f32x4 a0 = {0,0,0,0};
        a0 = MFMA(fh0, bh[0], a0); a0 = MFMA(fh0, bl[0], a0);
        a0 = MFMA(fh1, bh[1], a0); a0 = MFMA(fh1, bl[1], a0);
        a0 = MFMA(rh0, bh[2], a0); a0 = MFMA(rh0, bl[2], a0);
        a0 = MFMA(rh1, bh[3], a0); a0 = MFMA(rh1, bl[3], a0);
        const int rbase = mt*16 + rq;
        #pragma unroll
        for (int r = 0; r < 4; ++r) {
          int row = rbase + r;
          if (row >= 40) break;
          float v = a0[r] + bo;
          s_seq[row*SF + n0] = v;
          if (L == 3) s_xnb[row*SB + n0] = f2bf(v);
        }
      }
    }
    __syncthreads();
  }

  // ---------------- Attention tail (token 0 only consumed downstream) ----------------
  {
    #pragma unroll 1
    for (int i = 0; i < 7; ++i) {
      const int u = wv + 4*i;
      int jt, mt;
      if (u < 4) { jt = u; mt = 0; }
      else { int v = u - 4; jt = 4 + (v & 7); mt = v >> 3; }
      const int j = jt*16 + arow;
      const unsigned short* Wh = wsb + AI_HI + j*64;
      const unsigned short* Wl = wsb + AI_LO + j*64;
      bf16x8 bh0 = ld8(Wh + aq), bh1 = ld8(Wh + 32 + aq);
      bf16x8 bl0 = ld8(Wl + aq), bl1 = ld8(Wl + 32 + aq);
      const float bj = aib[j];
      const unsigned short* A = s_xnb + (mt*16 + arow)*SB + aq;
      bf16x8 ah0 = ld8(A), ah1 = ld8(A + 32);
      f32x4 a0 = {0,0,0,0};
      a0 = MFMA(ah0, bh0, a0); a0 = MFMA(ah0, bl0, a0);
      a0 = MFMA(ah1, bh1, a0); a0 = MFMA(ah1, bl1, a0);
      const int rbase = mt*16 + rq;
      #pragma unroll
      for (int r = 0; r < 4; ++r) {
        int row = rbase + r;
        if (row >= 40) break;
        float val = a0[r] + bj;
        if (jt < 4) { if (row == 0) g0f[320 + j] = val; }
        else if (jt < 8) bB0[row*SB + (j - 64)] = f2bf(val);
        else bB1[row*SB + (j - 128)] = f2bf(val);
      }
    }
    if (tid >= 192) g0f[384 + (tid - 192)] = s_seq[tid - 192];
  }
  __syncthreads();

  // logits (8 heads x 40 keys) -> g0f[0..320)
  for (int e = tid; e < 320; e += 256) {
    int h = e / 40, kk = e - h*40;
    float acc = 0.f;
    #pragma unroll
    for (int i = 0; i < 8; ++i)
      acc += g0f[320 + h*8 + i] * bf2f(bB0[kk*SB + h*8 + i]);
    g0f[e] = acc * 0.35355339059327373f;
  }
  __syncthreads();

  // softmax: 2 heads per wave, 32 lanes per head
  {
    const int h = wv*2 + (lane >> 5), jl = lane & 31;
    float a = g0f[h*40 + jl];
    float bv = (jl < 8) ? g0f[h*40 + 32 + jl] : -1e30f;
    float m = fmaxf(a, bv);
    #pragma unroll
    for (int o = 16; o > 0; o >>= 1) m = fmaxf(m, __shfl_xor(m, o, 32));
    float pa = __expf(a - m), pb = (jl < 8) ? __expf(bv - m) : 0.f;
    float s = pa + pb;
    #pragma unroll
    for (int o = 16; o > 0; o >>= 1) s += __shfl_xor(s, o, 32);
    float inv = 1.f / s;
    g0f[h*40 + jl] = pa * inv;
    if (jl < 8) g0f[h*40 + 32 + jl] = pb * inv;
  }
  __syncthreads();

  // ao partials over 256 threads -> g1f[0..256)
  {
    const int d = tid & 63, qrt = tid >> 6, hh = d >> 3;
    float acc = 0.f;
    #pragma unroll
    for (int k = qrt*10; k < qrt*10 + 10; ++k)
      acc += g0f[hh*40 + k] * bf2f(bB1[k*SB + d]);
    g1f[qrt*64 + d] = acc;
  }
  __syncthreads();
  if (tid < 64) g1f[256 + tid] = g1f[tid] + g1f[64 + tid] + g1f[128 + tid] + g1f[192 + tid];
  __syncthreads();

  // c = seq0 + ao @ aoW.T + aob -> g0f[448..512)
  if (tid < 64)
    g0f[448 + tid] = g0f[384 + tid] + aob[tid] + dotg64(&g1f[256], aoW + (size_t)tid*64);
  __syncthreads();

  // MLP1 -> g1f[320..448)
  if (tid < 128)
    g1f[320 + tid] = fmaxf(b1[tid] + dotg64(&g0f[448], w1 + (size_t)tid*64), 0.f);
  __syncthreads();

  // MLP2 -> g1f[448..512)
  if (tid < 64) {
    float acc = dotg64(&g1f[320], w2 + (size_t)tid*128)
              + dotg64(&g1f[384], w2 + (size_t)tid*128 + 64);
    g1f[448 + tid] = fmaxf(acc + b2[tid], 0.f);
  }
  __syncthreads();

  if (tid < 64) {
    float v = g1f[448 + tid] * w3[tid];
    v = wred64(v);
    if (tid == 0) out[b] = v + b3[0];
  }
}

extern "C" void kernel_launch(void* const* d_in, const int* in_sizes, int n_in,
                              void* d_out, int out_size, void* d_ws, size_t ws_size,
                              hipStream_t stream) {
  (void)n_in; (void)ws_size; (void)out_size;
  const float* dense_x = (const float*)d_in[0];
  const float* dense_W = (const float*)d_in[1];
  const float* dense_b = (const float*)d_in[2];
  const float* tbl     = (const float*)d_in[3];
  const float* cls     = (const float*)d_in[4];
  const float* ng      = (const float*)d_in[5];
  const float* nb      = (const float*)d_in[6];
  const float* xW      = (const float*)d_in[7];
  const float* xb      = (const float*)d_in[8];
  const float* Ap      = (const float*)d_in[9];
  const float* Dp      = (const float*)d_in[10];
  const float* oW      = (const float*)d_in[11];
  const float* ob      = (const float*)d_in[12];
  const float* mW      = (const float*)d_in[13];
  const float* mb      = (const float*)d_in[14];
  const float* aiW     = (const float*)d_in[15];
  const float* aib     = (const float*)d_in[16];
  const float* aoW     = (const float*)d_in[17];
  const float* aob     = (const float*)d_in[18];
  const float* w1      = (const float*)d_in[19];
  const float* b1      = (const float*)d_in[20];
  const float* w2      = (const float*)d_in[21];
  const float* b2      = (const float*)d_in[22];
  const float* w3      = (const float*)d_in[23];
  const float* b3      = (const float*)d_in[24];
  const int*   sidx    = (const int*)d_in[25];
  float* out = (float*)d_out;
  unsigned short* wsb = (unsigned short*)d_ws;

  hipLaunchKernelGGL(prep_kernel, dim3(256), dim3(256), 0, stream,
                     xW, oW, mW, aiW, Ap, wsb);

  const int B = in_sizes[0] / 13;  // 1024
  hipLaunchKernelGGL(Mamba4CTRV3_kernel, dim3(B), dim3(256), 0, stream,
                     dense_x, dense_W, dense_b, tbl, cls, ng, nb, xb, Dp, ob, mb,
                     aib, aoW, aob, w1, b1, w2, b2, w3, b3, sidx, wsb, out);
}

// Round 9
// 273.038 us; speedup vs baseline: 1.1129x; 1.0192x over previous
//
#include <hip/hip_runtime.h>

#define DEV static __device__ __forceinline__

typedef __attribute__((ext_vector_type(8))) short bf16x8;
typedef __attribute__((ext_vector_type(4))) float f32x4;

#define MFMA(a, b, c) __builtin_amdgcn_mfma_f32_16x16x32_bf16(a, b, c, 0, 0, 0)

DEV float bf2f(unsigned short h) { return __uint_as_float(((unsigned)h) << 16); }
DEV unsigned short f2bf(float f) {
  unsigned u = __float_as_uint(f);
  u += 0x7fffu + ((u >> 16) & 1u);
  return (unsigned short)(u >> 16);
}
DEV bf16x8 ld8(const unsigned short* p) { return *(const bf16x8*)p; }

// chunked streaming dot: x in LDS (broadcast), weights streamed from global.
DEV float dotg64(const float* x, const float* wrow) {
  const float4* wp = (const float4*)wrow;
  float a0 = 0.f, a1 = 0.f;
  #pragma unroll
  for (int c = 0; c < 8; ++c) {
    float4 u = wp[2*c], v = wp[2*c + 1];
    a0 = fmaf(u.x, x[8*c+0], a0); a0 = fmaf(u.y, x[8*c+1], a0);
    a0 = fmaf(u.z, x[8*c+2], a0); a0 = fmaf(u.w, x[8*c+3], a0);
    a1 = fmaf(v.x, x[8*c+4], a1); a1 = fmaf(v.y, x[8*c+5], a1);
    a1 = fmaf(v.z, x[8*c+6], a1); a1 = fmaf(v.w, x[8*c+7], a1);
  }
  return a0 + a1;
}
DEV float wred64(float v) {
  #pragma unroll
  for (int o = 32; o > 0; o >>= 1) v += __shfl_xor(v, o, 64);
  return v;
}

// d_ws layout (ushort element offsets): weights as bf16 hi/lo pairs
#define XW_HI 0        // 4*2*128*64 = 65536
#define XW_LO 65536
#define OW_HI 131072   // 4*2*64*64 = 32768
#define OW_LO 163840
#define MW_HI 196608   // 4*64*128 = 32768
#define MW_LO 229376
#define AI_HI 262144   // 192*64 = 12288
#define AI_LO 274432
#define SC_OFF 286720  // f32 region: 8*256 gate-poly coefs

#define SF 68  // f32 seq row stride
#define SB 72  // bf16 row stride (16B-aligned rows for ds_read_b128)

__global__ void prep_kernel(const float* __restrict__ xW, const float* __restrict__ oW,
                            const float* __restrict__ mW, const float* __restrict__ aiW,
                            const float* __restrict__ Ap, unsigned short* __restrict__ wsb) {
  const int gid = blockIdx.x * blockDim.x + threadIdx.x;
  const int stride = gridDim.x * blockDim.x;
  for (int i = gid; i < 65536; i += stride) {
    float x = xW[i]; unsigned short h = f2bf(x);
    wsb[XW_HI + i] = h; wsb[XW_LO + i] = f2bf(x - bf2f(h));
  }
  for (int i = gid; i < 32768; i += stride) {
    float x = oW[i]; unsigned short h = f2bf(x);
    wsb[OW_HI + i] = h; wsb[OW_LO + i] = f2bf(x - bf2f(h));
  }
  for (int i = gid; i < 32768; i += stride) {
    float x = mW[i]; unsigned short h = f2bf(x);
    wsb[MW_HI + i] = h; wsb[MW_LO + i] = f2bf(x - bf2f(h));
  }
  for (int i = gid; i < 12288; i += stride) {
    float x = aiW[i]; unsigned short h = f2bf(x);
    wsb[AI_HI + i] = h; wsb[AI_LO + i] = f2bf(x - bf2f(h));
  }
  float* sc = (float*)(wsb + SC_OFF);
  for (int i = gid; i < 512; i += stride) {
    int pi = i >> 6, d = i & 63;
    const float* a = Ap + (size_t)i * 16;
    float s1 = 0, s2 = 0, s3 = 0, s4 = 0;
    #pragma unroll
    for (int n = 0; n < 16; ++n) {
      float z = a[n]; float z2 = z * z;
      s1 += z; s2 += z2; s3 += z2 * z; s4 += z2 * z2;
    }
    sc[pi*256 + d]       = s1;
    sc[pi*256 + 64 + d]  = s2 * 0.5f;
    sc[pi*256 + 128 + d] = s3 * (1.f/6.f);
    sc[pi*256 + 192 + d] = s4 * (1.f/24.f);
  }
}

// 2 batch rows per 512-thread block: 80 tokens = exactly 5 MFMA row-tiles
// (no padding waste, no row guards), barriers amortized over 2 rows.
// launch_bounds rule (measured): VGPR cap = 512/(2*arg) -> (512,2) = 128.
// LDS 81,408 B -> 2 blocks/CU (162,816 <= 163,840) = 16 waves/CU, needs
// VGPR <= 128 (R8 structure used 100).
__global__ __launch_bounds__(512, 2)
void Mamba4CTRV3_kernel(
    const float* __restrict__ dense_x, const float* __restrict__ dense_W,
    const float* __restrict__ dense_b, const float* __restrict__ tbl,
    const float* __restrict__ cls, const float* __restrict__ ng,
    const float* __restrict__ nb, const float* __restrict__ xb,
    const float* __restrict__ Dp, const float* __restrict__ ob,
    const float* __restrict__ mb, const float* __restrict__ aib,
    const float* __restrict__ aoW, const float* __restrict__ aob,
    const float* __restrict__ w1, const float* __restrict__ b1,
    const float* __restrict__ w2, const float* __restrict__ b2,
    const float* __restrict__ w3, const float* __restrict__ b3,
    const int* __restrict__ sidx, const unsigned short* __restrict__ wsb,
    float* __restrict__ out) {
  __shared__ __align__(16) unsigned char smem[81408];
  float*          s_seq  = (float*)smem;                     // 80xSF f32 residual spine
  unsigned short* s_xnb  = (unsigned short*)(smem + 21760);  // 80xSB bf16 xn / final seq
  unsigned short* bG0    = (unsigned short*)(smem + 33280);  // gate0 -> out0 ; tail f32 scratch A
  unsigned short* bG1    = (unsigned short*)(smem + 44800);  // gate1 -> out1 ; tail f32 scratch B
  unsigned short* bB0    = (unsigned short*)(smem + 56320);  // Bm0 -> f-branch ; tail: K
  unsigned short* bB1    = (unsigned short*)(smem + 67840);  // Bm1 -> r-branch ; tail: V
  float*          s_small= (float*)(smem + 79360);           // 512 f32
  float* g0f = (float*)bG0;   // tail: per-row 720 f32 {probs320, q64, seq0_64, c64}
  float* g1f = (float*)bG1;   // tail: per-row 512 f32 {aopart256, ao64, mlp1_128, mlp2_64}
  const float* scf = (const float*)(wsb + SC_OFF);

  const int tid = threadIdx.x, b = blockIdx.x;
  const int lane = tid & 63, wv = tid >> 6;  // wv 0..7
  const int arow = lane & 15;      // A-frag row / C-frag col
  const int aq = (lane >> 4) * 8;  // A-frag k offset
  const int rq = (lane >> 4) * 4;  // C-frag row base

  // ---------------- Phase 0: build seq for both rows ----------------
  {
    float* s_dx = s_small;               // [0..13) row0, [16..29) row1
    int* s_idx = (int*)(s_small + 32);   // 52 ints
    if (tid < 13) s_dx[tid] = dense_x[(b*2)*13 + tid];
    else if (tid >= 16 && tid < 29) s_dx[tid] = dense_x[(b*2+1)*13 + (tid-16)];
    if (tid >= 64 && tid < 116) {
      int s = tid - 64, br = s / 26, si = s - br*26;
      int v = sidx[(b*2+br)*26 + si];
      v = v < 0 ? 0 : (v > 10000 ? 10000 : v);
      s_idx[s] = v;
    }
    __syncthreads();
    if (tid < 128) s_seq[(tid>>6)*40*SF + (tid&63)] = cls[tid&63];
    {
      const int br = tid >> 8, j0 = tid & 255;
      float x[13];
      #pragma unroll
      for (int k = 0; k < 13; ++k) x[k] = s_dx[br*16 + k];
      for (int j = j0; j < 832; j += 256) {
        float acc = dense_b[j];
        #pragma unroll
        for (int k = 0; k < 13; ++k) acc = fmaf(x[k], dense_W[j*13 + k], acc);
        s_seq[(br*40 + 1 + (j >> 6)) * SF + (j & 63)] = acc;
      }
    }
    for (int e = tid; e < 832; e += 512) {
      int br = e / 416, rem = e - br*416, s = rem >> 4, c = rem & 15;
      const float4* row = (const float4*)(tbl + ((size_t)(s*10001 + s_idx[br*26 + s]))*64);
      ((float4*)&s_seq[(br*40 + 14 + s) * SF])[c] = row[c];
    }
  }
  __syncthreads();

  // ---------------- 4 bidirectional mamba layers (dirs + rows fused) ----------------
  for (int L = 0; L < 4; ++L) {
    const int pi0 = 2*L, pi1 = 2*L + 1;

    // LN once per layer, 80 tokens over 8 waves
    {
      const int half = lane >> 5, dl = lane & 31;
      for (int it = 0; it < 5; ++it) {
        int t = wv*10 + it*2 + half;  // 0..79
        int e = t*SF + dl;
        float x0 = s_seq[e], x1 = s_seq[e + 32];
        float s = x0 + x1, q = fmaf(x0, x0, x1*x1);
        #pragma unroll
        for (int o = 16; o > 0; o >>= 1) { s += __shfl_xor(s, o, 64); q += __shfl_xor(q, o, 64); }
        float mean = s * (1.f/64.f);
        float var = q * (1.f/64.f) - mean*mean;
        float rs = rsqrtf(var + 1e-5f);
        float xn0 = fmaf((x0 - mean) * rs, ng[pi0*64 + dl], nb[pi0*64 + dl]);
        float xn1 = fmaf((x1 - mean) * rs, ng[pi0*64 + dl + 32], nb[pi0*64 + dl + 32]);
        int eb = t*SB + dl;
        s_xnb[eb] = f2bf(xn0); s_xnb[eb + 32] = f2bf(xn1);
      }
    }
    __syncthreads();

    // xproj both dirs, single pass: wave w -> col-tile w (delta w<4, Bm w>=4), 5 mt
    {
      const int j = wv*16 + arow;  // 0..127
      const unsigned short* Wh0 = wsb + XW_HI + pi0*8192 + j*64;
      const unsigned short* Wl0 = wsb + XW_LO + pi0*8192 + j*64;
      const unsigned short* Wh1 = wsb + XW_HI + pi1*8192 + j*64;
      const unsigned short* Wl1 = wsb + XW_LO + pi1*8192 + j*64;
      bf16x8 bh00 = ld8(Wh0 + aq), bh01 = ld8(Wh0 + 32 + aq);
      bf16x8 bl00 = ld8(Wl0 + aq), bl01 = ld8(Wl0 + 32 + aq);
      bf16x8 bh10 = ld8(Wh1 + aq), bh11 = ld8(Wh1 + 32 + aq);
      bf16x8 bl10 = ld8(Wl1 + aq), bl11 = ld8(Wl1 + 32 + aq);
      const float bj0 = xb[pi0*128 + j], bj1 = xb[pi1*128 + j];
      const bool isDelta = (wv < 4);  // wave-uniform
      float c10=0,c20=0,c30=0,c40=0,c11=0,c21=0,c31=0,c41=0;
      if (isDelta) {
        c10=scf[pi0*256+j]; c20=scf[pi0*256+64+j]; c30=scf[pi0*256+128+j]; c40=scf[pi0*256+192+j];
        c11=scf[pi1*256+j]; c21=scf[pi1*256+64+j]; c31=scf[pi1*256+128+j]; c41=scf[pi1*256+192+j];
      }
      for (int mt = 0; mt < 5; ++mt) {
        const unsigned short* A = s_xnb + (mt*16 + arow)*SB + aq;
        bf16x8 ah0 = ld8(A), ah1 = ld8(A + 32);
        f32x4 a0 = {0,0,0,0}, a1 = {0,0,0,0};
        a0 = MFMA(ah0, bh00, a0); a0 = MFMA(ah0, bl00, a0);
        a0 = MFMA(ah1, bh01, a0); a0 = MFMA(ah1, bl01, a0);
        a1 = MFMA(ah0, bh10, a1); a1 = MFMA(ah0, bl10, a1);
        a1 = MFMA(ah1, bh11, a1); a1 = MFMA(ah1, bl11, a1);
        const int rbase = mt*16 + rq;
        #pragma unroll
        for (int r = 0; r < 4; ++r) {
          int row = rbase + r;  // 0..79, exact
          float x0v = a0[r] + bj0, x1v = a1[r] + bj1;
          if (isDelta) {
            float sp0 = fmaxf(x0v, 0.f) + __logf(1.f + __expf(-fabsf(x0v)));
            float sp1 = fmaxf(x1v, 0.f) + __logf(1.f + __expf(-fabsf(x1v)));
            bG0[row*SB + j] = f2bf(sp0 * fmaf(sp0, fmaf(sp0, fmaf(sp0, c40, c30), c20), c10));
            bG1[row*SB + j] = f2bf(sp1 * fmaf(sp1, fmaf(sp1, fmaf(sp1, c41, c31), c21), c11));
          } else {
            int d = j - 64;
            bB0[row*SB + d] = f2bf(x0v);
            bB1[row*SB + d] = f2bf(x1v);
          }
        }
      }
    }
    __syncthreads();

    // Scan, two-pass recompute: (row, seg, dir, d) = 512 items, one per thread
    {
      const int d = tid & 63, dir = (tid >> 6) & 1, seg = (tid >> 7) & 1, br = tid >> 8;
      const int base = br*40;
      const unsigned short* bmb = dir ? bB1 : bB0;
      float run = 0.f;
      #pragma unroll
      for (int k = 0; k < 20; ++k) {
        int t = base + (dir ? (39 - (seg*20 + k)) : (seg*20 + k));
        run = fmaf(bf2f(s_xnb[t*SB + d]), bf2f(bmb[t*SB + d]), run);
      }
      s_small[br*256 + seg*128 + dir*64 + d] = run;
      __syncthreads();
      unsigned short* gb = dir ? bG1 : bG0;
      const float off = seg ? s_small[br*256 + dir*64 + d] : 0.f;
      const float dpd = Dp[(2*L + dir)*64 + d];
      run = off;
      #pragma unroll
      for (int k = 0; k < 20; ++k) {
        int t = base + (dir ? (39 - (seg*20 + k)) : (seg*20 + k));
        float xn = bf2f(s_xnb[t*SB + d]);
        run = fmaf(xn, bf2f(bmb[t*SB + d]), run);
        float gate = 16.f + bf2f(gb[t*SB + d]);
        gb[t*SB + d] = f2bf(fmaf(run, gate, xn * dpd));
      }
    }
    __syncthreads();

    // outproj both dirs + residual: 4 col-tiles x 5 mt over 8 waves
    {
      const int j = (wv & 3)*16 + arow;
      const int mt0 = (wv < 4) ? 0 : 3, mt1 = (wv < 4) ? 3 : 5;
      const unsigned short* Wh0 = wsb + OW_HI + pi0*4096 + j*64;
      const unsigned short* Wl0 = wsb + OW_LO + pi0*4096 + j*64;
      const unsigned short* Wh1 = wsb + OW_HI + pi1*4096 + j*64;
      const unsigned short* Wl1 = wsb + OW_LO + pi1*4096 + j*64;
      bf16x8 bh00 = ld8(Wh0 + aq), bh01 = ld8(Wh0 + 32 + aq);
      bf16x8 bl00 = ld8(Wl0 + aq), bl01 = ld8(Wl0 + 32 + aq);
      bf16x8 bh10 = ld8(Wh1 + aq), bh11 = ld8(Wh1 + 32 + aq);
      bf16x8 bl10 = ld8(Wl1 + aq), bl11 = ld8(Wl1 + 32 + aq);
      const float bo0 = ob[pi0*64 + j], bo1 = ob[pi1*64 + j];
      for (int mt = mt0; mt < mt1; ++mt) {
        const unsigned short* A0 = bG0 + (mt*16 + arow)*SB + aq;
        const unsigned short* A1 = bG1 + (mt*16 + arow)*SB + aq;
        bf16x8 a00 = ld8(A0), a01 = ld8(A0 + 32);
        bf16x8 a10 = ld8(A1), a11 = ld8(A1 + 32);
        f32x4 c0 = {0,0,0,0}, c1 = {0,0,0,0};
        c0 = MFMA(a00, bh00, c0); c0 = MFMA(a00, bl00, c0);
        c0 = MFMA(a01, bh01, c0); c0 = MFMA(a01, bl01, c0);
        c1 = MFMA(a10, bh10, c1); c1 = MFMA(a10, bl10, c1);
        c1 = MFMA(a11, bh11, c1); c1 = MFMA(a11, bl11, c1);
        const int rbase = mt*16 + rq;
        #pragma unroll
        for (int r = 0; r < 4; ++r) {
          int row = rbase + r;
          float res = s_seq[row*SF + j];
          bB0[row*SB + j] = f2bf(c0[r] + bo0 + res);
          bB1[row*SB + j] = f2bf(c1[r] + bo1 + res);
        }
      }
    }
    __syncthreads();

    // merge: 4 col-tiles x 5 mt over 8 waves
    {
      const int n0 = (wv & 3)*16 + arow;
      const int mt0 = (wv < 4) ? 0 : 3, mt1 = (wv < 4) ? 3 : 5;
      const unsigned short* Wh = wsb + MW_HI + L*8192 + n0*128;
      const unsigned short* Wl = wsb + MW_LO + L*8192 + n0*128;
      bf16x8 bh[4], bl[4];
      #pragma unroll
      for (int ks = 0; ks < 4; ++ks) { bh[ks] = ld8(Wh + ks*32 + aq); bl[ks] = ld8(Wl + ks*32 + aq); }
      const float bo = mb[L*64 + n0];
      for (int mt = mt0; mt < mt1; ++mt) {
        const unsigned short* Af = bB0 + (mt*16 + arow)*SB + aq;
        const unsigned short* Ar = bB1 + (mt*16 + arow)*SB + aq;
        bf16x8 fh0 = ld8(Af), fh1 = ld8(Af + 32);
        bf16x8 rh0 = ld8(Ar), rh1 = ld8(Ar + 32);
        f32x4 a0 = {0,0,0,0};
        a0 = MFMA(fh0, bh[0], a0); a0 = MFMA(fh0, bl[0], a0);
        a0 = MFMA(fh1, bh[1], a0); a0 = MFMA(fh1, bl[1], a0);
        a0 = MFMA(rh0, bh[2], a0); a0 = MFMA(rh0, bl[2], a0);
        a0 = MFMA(rh1, bh[3], a0); a0 = MFMA(rh1, bl[3], a0);
        const int rbase = mt*16 + rq;
        #pragma unroll
        for (int r = 0; r < 4; ++r) {
          int row = rbase + r;
          float v = a0[r] + bo;
          s_seq[row*SF + n0] = v;
          if (L == 3) s_xnb[row*SB + n0] = f2bf(v);
        }
      }
    }
    __syncthreads();
  }

  // ---------------- Attention tail (token 0 per row consumed downstream) ----------------
  // QKV: 48 units (KV: 8 ct x 5 mt; Q: 4 ct x mt{0,2}) over 8 waves = 6 each
  {
    #pragma unroll 1
    for (int i = 0; i < 6; ++i) {
      const int u = wv + 8*i;
      int j, mtk;
      if (u < 40) { j = 64 + (u & 7)*16 + arow; mtk = u >> 3; }
      else { int qi = u - 40; j = (qi & 3)*16 + arow; mtk = (qi >> 2) * 2; }
      const unsigned short* Wh = wsb + AI_HI + j*64;
      const unsigned short* Wl = wsb + AI_LO + j*64;
      bf16x8 bh0 = ld8(Wh + aq), bh1 = ld8(Wh + 32 + aq);
      bf16x8 bl0 = ld8(Wl + aq), bl1 = ld8(Wl + 32 + aq);
      const float bj = aib[j];
      const unsigned short* A = s_xnb + (mtk*16 + arow)*SB + aq;
      bf16x8 ah0 = ld8(A), ah1 = ld8(A + 32);
      f32x4 a0 = {0,0,0,0};
      a0 = MFMA(ah0, bh0, a0); a0 = MFMA(ah0, bl0, a0);
      a0 = MFMA(ah1, bh1, a0); a0 = MFMA(ah1, bl1, a0);
      const int rbase = mtk*16 + rq;
      #pragma unroll
      for (int r = 0; r < 4; ++r) {
        int row = rbase + r;
        float val = a0[r] + bj;
        if (u < 40) {
          if (j < 128) bB0[row*SB + (j - 64)] = f2bf(val);
          else         bB1[row*SB + (j - 128)] = f2bf(val);
        } else {
          if (row == 0)       g0f[320 + j] = val;
          else if (row == 40) g0f[720 + 320 + j] = val;
        }
      }
    }
    if (tid < 128) g0f[(tid>>6)*720 + 384 + (tid&63)] = s_seq[(tid>>6)*40*SF + (tid&63)];
  }
  __syncthreads();

  // logits: 2 rows x 8 heads x 40 keys = 640
  for (int e = tid; e < 640; e += 512) {
    int br = e / 320, rem = e - br*320;
    int h = rem / 40, kk = rem - h*40;
    float acc = 0.f;
    #pragma unroll
    for (int i = 0; i < 8; ++i)
      acc += g0f[br*720 + 320 + h*8 + i] * bf2f(bB0[(br*40 + kk)*SB + h*8 + i]);
    g0f[br*720 + rem] = acc * 0.35355339059327373f;
  }
  __syncthreads();

  // softmax: 16 heads over 8 waves, 32 lanes per head
  {
    const int hh = wv*2 + (lane >> 5), jl = lane & 31;
    float* pr = g0f + (hh >> 3)*720 + (hh & 7)*40;
    float a = pr[jl];
    float bv = (jl < 8) ? pr[32 + jl] : -1e30f;
    float m = fmaxf(a, bv);
    #pragma unroll
    for (int o = 16; o > 0; o >>= 1) m = fmaxf(m, __shfl_xor(m, o, 32));
    float pa = __expf(a - m), pb = (jl < 8) ? __expf(bv - m) : 0.f;
    float s = pa + pb;
    #pragma unroll
    for (int o = 16; o > 0; o >>= 1) s += __shfl_xor(s, o, 32);
    float inv = 1.f / s;
    pr[jl] = pa * inv;
    if (jl < 8) pr[32 + jl] = pb * inv;
  }
  __syncthreads();

  // ao partials: 2 rows x 4 quarters x 64 d = 512
  {
    const int d = tid & 63, qrt = (tid >> 6) & 3, br = tid >> 8, hh = d >> 3;
    float acc = 0.f;
    #pragma unroll
    for (int k = qrt*10; k < qrt*10 + 10; ++k)
      acc += g0f[br*720 + hh*40 + k] * bf2f(bB1[(br*40 + k)*SB + d]);
    g1f[br*512 + qrt*64 + d] = acc;
  }
  __syncthreads();
  if (tid < 128) {
    float* p = g1f + (tid >> 6)*512;
    int d = tid & 63;
    p[256 + d] = p[d] + p[64 + d] + p[128 + d] + p[192 + d];
  }
  __syncthreads();

  // c = seq0 + ao @ aoW.T + aob
  if (tid < 128) {
    int br = tid >> 6, o = tid & 63;
    g0f[br*720 + 448 + o] = g0f[br*720 + 384 + o] + aob[o]
                          + dotg64(&g1f[br*512 + 256], aoW + (size_t)o*64);
  }
  __syncthreads();

  // MLP1
  if (tid < 256) {
    int br = tid >> 7, o = tid & 127;
    g1f[br*512 + 320 + o] = fmaxf(b1[o] + dotg64(&g0f[br*720 + 448], w1 + (size_t)o*64), 0.f);
  }
  __syncthreads();

  // MLP2
  if (tid < 128) {
    int br = tid >> 6, o = tid & 63;
    float acc = dotg64(&g1f[br*512 + 320], w2 + (size_t)o*128)
              + dotg64(&g1f[br*512 + 384], w2 + (size_t)o*128 + 64);
    g1f[br*512 + 448 + o] = fmaxf(acc + b2[o], 0.f);
  }
  __syncthreads();

  if (tid < 128) {
    int br = tid >> 6;
    float v = g1f[br*512 + 448 + lane] * w3[lane];
    v = wred64(v);
    if (lane == 0) out[b*2 + br] = v + b3[0];
  }
}

extern "C" void kernel_launch(void* const* d_in, const int* in_sizes, int n_in,
                              void* d_out, int out_size, void* d_ws, size_t ws_size,
                              hipStream_t stream) {
  (void)n_in; (void)ws_size; (void)out_size;
  const float* dense_x = (const float*)d_in[0];
  const float* dense_W = (const float*)d_in[1];
  const float* dense_b = (const float*)d_in[2];
  const float* tbl     = (const float*)d_in[3];
  const float* cls     = (const float*)d_in[4];
  const float* ng      = (const float*)d_in[5];
  const float* nb      = (const float*)d_in[6];
  const float* xW      = (const float*)d_in[7];
  const float* xb      = (const float*)d_in[8];
  const float* Ap      = (const float*)d_in[9];
  const float* Dp      = (const float*)d_in[10];
  const float* oW      = (const float*)d_in[11];
  const float* ob      = (const float*)d_in[12];
  const float* mW      = (const float*)d_in[13];
  const float* mb      = (const float*)d_in[14];
  const float* aiW     = (const float*)d_in[15];
  const float* aib     = (const float*)d_in[16];
  const float* aoW     = (const float*)d_in[17];
  const float* aob     = (const float*)d_in[18];
  const float* w1      = (const float*)d_in[19];
  const float* b1      = (const float*)d_in[20];
  const float* w2      = (const float*)d_in[21];
  const float* b2      = (const float*)d_in[22];
  const float* w3      = (const float*)d_in[23];
  const float* b3      = (const float*)d_in[24];
  const int*   sidx    = (const int*)d_in[25];
  float* out = (float*)d_out;
  unsigned short* wsb = (unsigned short*)d_ws;

  hipLaunchKernelGGL(prep_kernel, dim3(256), dim3(256), 0, stream,
                     xW, oW, mW, aiW, Ap, wsb);

  const int B = in_sizes[0] / 13;  // 1024
  hipLaunchKernelGGL(Mamba4CTRV3_kernel, dim3(B/2), dim3(512), 0, stream,
                     dense_x, dense_W, dense_b, tbl, cls, ng, nb, xb, Dp, ob, mb,
                     aib, aoW, aob, w1, b1, w2, b2, w3, b3, sidx, wsb, out);
}